// Round 3
// baseline (726.340 us; speedup 1.0000x reference)
//
#include <hip/hip_runtime.h>
#include <hip/hip_bf16.h>

typedef __bf16 bf16x8 __attribute__((ext_vector_type(8)));
typedef __bf16 bf16x4 __attribute__((ext_vector_type(4)));
typedef float f32x4 __attribute__((ext_vector_type(4)));

#define BM 128
#define BN 128
#define BK 32

__device__ __forceinline__ void gload16(const __bf16* g, __bf16* l) {
    __builtin_amdgcn_global_load_lds((const __attribute__((address_space(1))) void*)g,
                                     (__attribute__((address_space(3))) void*)l, 16, 0, 0);
}

__device__ __forceinline__ float gelu_f(float v) {
    float z = 0.7978845608028654f * (v + 0.044715f * v * v * v);
    float e = __expf(2.f * z);
    return 0.5f * v * (2.f - 2.f / (e + 1.f));  // 0.5*v*(1+tanh(z)), overflow-safe
}

// XCD-chunk swizzle (bijective when nwg%8==0): each XCD gets a contiguous
// chunk of the flat grid, so blocks sharing operand panels co-reside in one L2.
__device__ __forceinline__ int xcd_swizzle(int flat, int nwg) {
    return (flat & 7) * (nwg >> 3) + (flat >> 3);
}

// ---------------- diagnostic fill (fp32 out) ----------------
__global__ __launch_bounds__(256) void diag_kernel(float* out, int n, float v) {
    int i = blockIdx.x * 256 + threadIdx.x;
    if (i < n) out[i] = v;
}

// ---------------- fused fp32->bf16 convert + transpose: in[K,N] -> out[N,K] ----------------
__global__ __launch_bounds__(256) void cvtT_kernel(
    const float* __restrict__ in, __bf16* __restrict__ out, int K, int N)
{
    __shared__ __bf16 tile[32][33];
    int bx = blockIdx.x * 32, by = blockIdx.y * 32;  // bx: n, by: k
    int tx = threadIdx.x & 31, ty = threadIdx.x >> 5;  // 32 x 8
#pragma unroll
    for (int i = 0; i < 32; i += 8)
        tile[ty + i][tx] = (__bf16)in[(size_t)(by + ty + i) * N + bx + tx];
    __syncthreads();
#pragma unroll
    for (int i = 0; i < 32; i += 8)
        out[(size_t)(bx + ty + i) * K + by + tx] = tile[tx][ty + i];
}

// ---------------- LayerNorm: fp32 in, bf16 out; one block per row of 1024 ----------------
__global__ __launch_bounds__(256) void ln_kernel(
    const float* __restrict__ x, const float* __restrict__ g,
    const float* __restrict__ bta, __bf16* __restrict__ out)
{
    const int row = blockIdx.x, t = threadIdx.x;
    const float* xr = x + (size_t)row * 1024;
    float4 xv = ((const float4*)xr)[t];
    float f[4] = {xv.x, xv.y, xv.z, xv.w};
    float s = f[0] + f[1] + f[2] + f[3];
    float ss = f[0]*f[0] + f[1]*f[1] + f[2]*f[2] + f[3]*f[3];
#pragma unroll
    for (int off = 32; off; off >>= 1) {
        s  += __shfl_xor(s, off, 64);
        ss += __shfl_xor(ss, off, 64);
    }
    __shared__ float red[8];
    int lane = t & 63, w = t >> 6;
    if (lane == 0) { red[w] = s; red[4 + w] = ss; }
    __syncthreads();
    s  = red[0] + red[1] + red[2] + red[3];
    ss = red[4] + red[5] + red[6] + red[7];
    float mu = s * (1.f / 1024.f);
    float var = ss * (1.f / 1024.f) - mu * mu;
    float rstd = rsqrtf(fmaxf(var, 0.f) + 1e-5f);
    float4 gv = ((const float4*)g)[t];
    float4 bv = ((const float4*)bta)[t];
    bf16x4 ov;
    ov[0] = (__bf16)((f[0] - mu) * rstd * gv.x + bv.x);
    ov[1] = (__bf16)((f[1] - mu) * rstd * gv.y + bv.y);
    ov[2] = (__bf16)((f[2] - mu) * rstd * gv.z + bv.z);
    ov[3] = (__bf16)((f[3] - mu) * rstd * gv.w + bv.w);
    ((bf16x4*)(out + (size_t)row * 1024))[t] = ov;
}

// ---------------- GEMM 128x128 (m97 + dbuf 2-phase + XCD swizzle) ----------------
// EPI: 0 bias, 1 bias+res(f32), 2 bias+gelu
// Used for ALL GEMMs: 64x64 per-wave tile keeps regs at ~120 (4 waves/SIMD),
// vs the 64x128 wide tile's ~220 (2 waves/SIMD) which starved latency hiding.
template <int EPI, bool OUT32>
__global__ __launch_bounds__(256, 4) void gemm_bt_kernel(
    const __bf16* __restrict__ A, const __bf16* __restrict__ BT,
    const float* __restrict__ bias, const float* __restrict__ res,
    void* __restrict__ Cp, int M, int N, int K)
{
    __shared__ __align__(16) __bf16 lA[2][BM * BK];  // phys = kc*1024 + row*8 + j
    __shared__ __align__(16) __bf16 lB[2][BN * BK];
    const int t = threadIdx.x;
    const int lane = t & 63;
    const int wave = t >> 6;
    const int wm = wave >> 1, wn = wave & 1;
    const int q4 = lane >> 4, r16 = lane & 15;
    // XCD swizzle: columns fastest within each XCD's contiguous chunk
    const int nwg = gridDim.x * gridDim.y;
    const int nf = xcd_swizzle(blockIdx.y * gridDim.x + blockIdx.x, nwg);
    const int bm = (nf / gridDim.x) * BM, bn = (nf % gridDim.x) * BN;

    const int srow = t & 127;
    const int skc = t >> 7;
    const __bf16* ga0 = A + (size_t)(bm + srow) * K + skc * 8;
    const __bf16* ga1 = ga0 + 16;
    const __bf16* gb0 = BT + (size_t)(bn + srow) * K + skc * 8;
    const __bf16* gb1 = gb0 + 16;

    f32x4 acc[4][4];
    f32x4 zero4 = {0.f, 0.f, 0.f, 0.f};
#pragma unroll
    for (int mi = 0; mi < 4; ++mi)
#pragma unroll
        for (int ni = 0; ni < 4; ++ni) acc[mi][ni] = zero4;

    // prologue: stage tile 0 into buf 0
    gload16(ga0, &lA[0][t * 8]);
    gload16(ga1, &lA[0][t * 8 + 2048]);
    gload16(gb0, &lB[0][t * 8]);
    gload16(gb1, &lB[0][t * 8 + 2048]);
    ga0 += BK; ga1 += BK; gb0 += BK; gb1 += BK;
    __syncthreads();  // drains vmcnt, tile 0 visible

    const int nk = K / BK;
    int cur = 0;
    for (int it = 0; it < nk; ++it) {
        if (it + 1 < nk) {  // issue next tile's loads BEFORE computing current
            gload16(ga0, &lA[cur ^ 1][t * 8]);
            gload16(ga1, &lA[cur ^ 1][t * 8 + 2048]);
            gload16(gb0, &lB[cur ^ 1][t * 8]);
            gload16(gb1, &lB[cur ^ 1][t * 8 + 2048]);
            ga0 += BK; ga1 += BK; gb0 += BK; gb1 += BK;
        }
        bf16x8 af[4], bfr[4];
#pragma unroll
        for (int i = 0; i < 4; ++i)
            af[i] = *(const bf16x8*)&lA[cur][q4 * 1024 + (wm * 64 + i * 16 + r16) * 8];
#pragma unroll
        for (int i = 0; i < 4; ++i)
            bfr[i] = *(const bf16x8*)&lB[cur][q4 * 1024 + (wn * 64 + i * 16 + r16) * 8];
#pragma unroll
        for (int mi = 0; mi < 4; ++mi)
#pragma unroll
            for (int ni = 0; ni < 4; ++ni)
                acc[mi][ni] = __builtin_amdgcn_mfma_f32_16x16x32_bf16(
                    af[mi], bfr[ni], acc[mi][ni], 0, 0, 0);
        if (it + 1 < nk) __syncthreads();  // next tile staged + cur reads done
        cur ^= 1;
    }

#pragma unroll
    for (int mi = 0; mi < 4; ++mi) {
#pragma unroll
        for (int ni = 0; ni < 4; ++ni) {
#pragma unroll
            for (int i = 0; i < 4; ++i) {
                int r = bm + wm * 64 + mi * 16 + q4 * 4 + i;
                int c = bn + wn * 64 + ni * 16 + r16;
                float v = acc[mi][ni][i] + bias[c];
                if (EPI == 1) v += res[(size_t)r * N + c];
                if (EPI == 2) v = gelu_f(v);
                if (OUT32) ((float*)Cp)[(size_t)r * N + c] = v;
                else       ((__bf16*)Cp)[(size_t)r * N + c] = (__bf16)v;
            }
        }
    }
}

// ---------------- Flash attention (causal), HD=64, T=2048, NH=16 ----------------
__global__ __launch_bounds__(256, 4) void attn_kernel(
    const __bf16* __restrict__ qkv, __bf16* __restrict__ attnb)
{
    __shared__ __align__(16) __bf16 lK[8192];    // phys = (d>>3)*1024 + key*8 + (d&7)
    __shared__ __align__(16) __bf16 lV[8192];    // phys = (key>>3)*512 + d*8 + (key&7)
    __shared__ __align__(16) __bf16 lP[4][512];  // per-wave 32-key chunk

    const int t = threadIdx.x, lane = t & 63, w = t >> 6;
    const int q4 = lane >> 4, r16 = lane & 15;
    // XCD swizzle: each XCD owns 8 consecutive (b,h) pairs across all 16 q-tiles,
    // so the K/V panels it streams stay resident in its own L2.
    const int nf = xcd_swizzle(blockIdx.y * 16 + blockIdx.x, 1024);
    const int qt = nf & 15;
    const int bh = nf >> 4;
    const int b = bh >> 4, h = bh & 15;
    const int qb = qt * 128;
    const __bf16* Qb = qkv + (size_t)b * 2048 * 3072 + h * 64;
    const __bf16* Kb = Qb + 1024;
    const __bf16* Vb = Qb + 2048;

    bf16x8 qf[2][2];
#pragma unroll
    for (int p = 0; p < 2; ++p) {
        int qrow = qb + p * 64 + w * 16 + r16;
        qf[p][0] = *(const bf16x8*)(Qb + (size_t)qrow * 3072 + q4 * 8);
        qf[p][1] = *(const bf16x8*)(Qb + (size_t)qrow * 3072 + 32 + q4 * 8);
#pragma unroll
        for (int j = 0; j < 8; ++j) {
            qf[p][0][j] = (__bf16)((float)qf[p][0][j] * 0.125f);
            qf[p][1][j] = (__bf16)((float)qf[p][1][j] * 0.125f);
        }
    }

    f32x4 zero4 = {0.f, 0.f, 0.f, 0.f};
    f32x4 o[2][4];
    float rs[2][4];
#pragma unroll
    for (int p = 0; p < 2; ++p)
#pragma unroll
        for (int i = 0; i < 4; ++i) { o[p][i] = zero4; rs[p][i] = 0.f; }

    const int skey = t & 127;
    const int vkc = t >> 6, svd = t & 63;

    for (int kb = 0; kb < qb + 128; kb += 128) {
        __syncthreads();
#pragma unroll
        for (int c = 0; c < 4; ++c)
            gload16(Kb + (size_t)(kb + skey) * 3072 + (c * 2 + (t >> 7)) * 8,
                    &lK[c * 2048 + t * 8]);
#pragma unroll
        for (int c = 0; c < 4; ++c) {
            int kc = c * 4 + vkc;
            bf16x8 vt;
#pragma unroll
            for (int j = 0; j < 8; ++j)
                vt[j] = Vb[(size_t)(kb + kc * 8 + j) * 3072 + svd];
            *(bf16x8*)&lV[kc * 512 + svd * 8] = vt;
        }
        __syncthreads();

#pragma unroll
        for (int p = 0; p < 2; ++p) {
            const int row0 = qb + p * 64 + w * 16 + q4 * 4;
            const bool interior = (kb + 127) <= (qb + p * 64 + w * 16);  // wave-uniform

            f32x4 s[8];
#pragma unroll
            for (int kg = 0; kg < 8; ++kg) {
                bf16x8 kfA = *(const bf16x8*)&lK[q4 * 1024 + (kg * 16 + r16) * 8];
                bf16x8 kfB = *(const bf16x8*)&lK[(4 + q4) * 1024 + (kg * 16 + r16) * 8];
                s[kg] = __builtin_amdgcn_mfma_f32_16x16x32_bf16(qf[p][0], kfA, zero4, 0, 0, 0);
                s[kg] = __builtin_amdgcn_mfma_f32_16x16x32_bf16(qf[p][1], kfB, s[kg], 0, 0, 0);
            }

#pragma unroll
            for (int kg = 0; kg < 8; ++kg)
#pragma unroll
                for (int i = 0; i < 4; ++i) {
                    float e = __expf(fminf(s[kg][i], 75.f));
                    if (!interior && (kb + kg * 16 + r16) > (row0 + i)) e = 0.f;
                    s[kg][i] = e;
                    rs[p][i] += e;
                }

#pragma unroll
            for (int c = 0; c < 4; ++c) {
#pragma unroll
                for (int kh = 0; kh < 2; ++kh)
#pragma unroll
                    for (int i = 0; i < 4; ++i)
                        lP[w][(kh * 2 + (r16 >> 3)) * 128 + (q4 * 4 + i) * 8 + (r16 & 7)] =
                            (__bf16)s[c * 2 + kh][i];
                asm volatile("s_waitcnt lgkmcnt(0)" ::: "memory");
                bf16x8 pf = *(const bf16x8*)&lP[w][q4 * 128 + r16 * 8];
#pragma unroll
                for (int ci = 0; ci < 4; ++ci) {
                    bf16x8 vf = *(const bf16x8*)&lV[(c * 4 + q4) * 512 + (ci * 16 + r16) * 8];
                    o[p][ci] = __builtin_amdgcn_mfma_f32_16x16x32_bf16(pf, vf, o[p][ci], 0, 0, 0);
                }
            }
        }
    }

#pragma unroll
    for (int p = 0; p < 2; ++p) {
#pragma unroll
        for (int off = 8; off; off >>= 1)
#pragma unroll
            for (int i = 0; i < 4; ++i) rs[p][i] += __shfl_xor(rs[p][i], off, 64);
#pragma unroll
        for (int ci = 0; ci < 4; ++ci)
#pragma unroll
            for (int i = 0; i < 4; ++i) {
                int trow = qb + p * 64 + w * 16 + q4 * 4 + i;
                float inv_l = (rs[p][i] > 0.f) ? (1.f / rs[p][i]) : 0.f;
                attnb[(size_t)(b * 2048 + trow) * 1024 + h * 64 + ci * 16 + r16] =
                    (__bf16)(o[p][ci][i] * inv_l);
            }
    }
}

// ---------------- launcher ----------------
extern "C" void kernel_launch(void* const* d_in, const int* in_sizes, int n_in,
                              void* d_out, int out_size, void* d_ws, size_t ws_size,
                              hipStream_t stream)
{
    const float* x      = (const float*)d_in[0];
    const float* ln1_g  = (const float*)d_in[1];
    const float* ln1_b  = (const float*)d_in[2];
    const float* w_qkv  = (const float*)d_in[3];
    const float* b_qkv  = (const float*)d_in[4];
    const float* w_proj = (const float*)d_in[5];
    const float* b_proj = (const float*)d_in[6];
    const float* ln2_g  = (const float*)d_in[7];
    const float* ln2_b  = (const float*)d_in[8];
    const float* w_fc   = (const float*)d_in[9];
    const float* b_fc   = (const float*)d_in[10];
    const float* w_mlp  = (const float*)d_in[11];
    const float* b_mlp  = (const float*)d_in[12];
    float* out = (float*)d_out;

    const size_t MiB = (size_t)1 << 20;
    if (ws_size < 136 * MiB) {
        float v = 1000.f + (float)(ws_size >> 20);
        diag_kernel<<<(out_size + 255) / 256, 256, 0, stream>>>(out, out_size, v);
        return;
    }

    char* ws = (char*)d_ws;
    __bf16* bufA   = (__bf16*)(ws);              // 16 MiB: h -> attnb -> h2
    __bf16* bufB   = (__bf16*)(ws + 16 * MiB);   // 64 MiB: qkvb(48) -> ffb(64)
    float*  x1     = (float*) (ws + 80 * MiB);   // 32 MiB fp32 residual
    __bf16* wqkvT  = (__bf16*)(ws + 112 * MiB);  // 6 MiB
    __bf16* wprojT = (__bf16*)(ws + 118 * MiB);  // 2 MiB
    __bf16* wfcT   = (__bf16*)(ws + 120 * MiB);  // 8 MiB
    __bf16* wmlpT  = (__bf16*)(ws + 128 * MiB);  // 8 MiB

    cvtT_kernel<<<dim3(96, 32),  256, 0, stream>>>(w_qkv,  wqkvT,  1024, 3072);
    cvtT_kernel<<<dim3(32, 32),  256, 0, stream>>>(w_proj, wprojT, 1024, 1024);
    cvtT_kernel<<<dim3(128, 32), 256, 0, stream>>>(w_fc,   wfcT,   1024, 4096);
    cvtT_kernel<<<dim3(32, 128), 256, 0, stream>>>(w_mlp,  wmlpT,  4096, 1024);

    ln_kernel<<<8192, 256, 0, stream>>>(x, ln1_g, ln1_b, bufA);
    gemm_bt_kernel<0, false><<<dim3(24, 64), 256, 0, stream>>>(
        bufA, wqkvT, b_qkv, nullptr, bufB, 8192, 3072, 1024);
    attn_kernel<<<dim3(16, 64), 256, 0, stream>>>(bufB, bufA);
    gemm_bt_kernel<1, true><<<dim3(8, 64), 256, 0, stream>>>(
        bufA, wprojT, b_proj, x, x1, 8192, 1024, 1024);
    ln_kernel<<<8192, 256, 0, stream>>>(x1, ln2_g, ln2_b, bufA);
    gemm_bt_kernel<2, false><<<dim3(32, 64), 256, 0, stream>>>(
        bufA, wfcT, b_fc, nullptr, bufB, 8192, 4096, 1024);
    gemm_bt_kernel<1, true><<<dim3(8, 64), 256, 0, stream>>>(
        bufB, wmlpT, b_mlp, x1, out, 8192, 1024, 4096);
}

// Round 4
// 686.848 us; speedup vs baseline: 1.0575x; 1.0575x over previous
//
#include <hip/hip_runtime.h>
#include <hip/hip_bf16.h>

typedef __bf16 bf16x8 __attribute__((ext_vector_type(8)));
typedef __bf16 bf16x4 __attribute__((ext_vector_type(4)));
typedef float f32x4 __attribute__((ext_vector_type(4)));

#define BM 128
#define BN 128
#define BK 32

__device__ __forceinline__ void gload16(const __bf16* g, __bf16* l) {
    __builtin_amdgcn_global_load_lds((const __attribute__((address_space(1))) void*)g,
                                     (__attribute__((address_space(3))) void*)l, 16, 0, 0);
}

__device__ __forceinline__ float gelu_f(float v) {
    float z = 0.7978845608028654f * (v + 0.044715f * v * v * v);
    float e = __expf(2.f * z);
    return 0.5f * v * (2.f - 2.f / (e + 1.f));  // 0.5*v*(1+tanh(z)), overflow-safe
}

// XCD-chunk swizzle (bijective when nwg%8==0)
__device__ __forceinline__ int xcd_swizzle(int flat, int nwg) {
    return (flat & 7) * (nwg >> 3) + (flat >> 3);
}

// ---------------- diagnostic fill (fp32 out) ----------------
__global__ __launch_bounds__(256) void diag_kernel(float* out, int n, float v) {
    int i = blockIdx.x * 256 + threadIdx.x;
    if (i < n) out[i] = v;
}

// ---------------- fused fp32->bf16 convert + transpose: in[K,N] -> out[N,K] ----------------
__global__ __launch_bounds__(256) void cvtT_kernel(
    const float* __restrict__ in, __bf16* __restrict__ out, int K, int N)
{
    __shared__ __bf16 tile[32][33];
    int bx = blockIdx.x * 32, by = blockIdx.y * 32;
    int tx = threadIdx.x & 31, ty = threadIdx.x >> 5;
#pragma unroll
    for (int i = 0; i < 32; i += 8)
        tile[ty + i][tx] = (__bf16)in[(size_t)(by + ty + i) * N + bx + tx];
    __syncthreads();
#pragma unroll
    for (int i = 0; i < 32; i += 8)
        out[(size_t)(bx + ty + i) * K + by + tx] = tile[tx][ty + i];
}

// ---------------- LayerNorm: fp32 in, bf16 out ----------------
__global__ __launch_bounds__(256) void ln_kernel(
    const float* __restrict__ x, const float* __restrict__ g,
    const float* __restrict__ bta, __bf16* __restrict__ out)
{
    const int row = blockIdx.x, t = threadIdx.x;
    const float* xr = x + (size_t)row * 1024;
    float4 xv = ((const float4*)xr)[t];
    float f[4] = {xv.x, xv.y, xv.z, xv.w};
    float s = f[0] + f[1] + f[2] + f[3];
    float ss = f[0]*f[0] + f[1]*f[1] + f[2]*f[2] + f[3]*f[3];
#pragma unroll
    for (int off = 32; off; off >>= 1) {
        s  += __shfl_xor(s, off, 64);
        ss += __shfl_xor(ss, off, 64);
    }
    __shared__ float red[8];
    int lane = t & 63, w = t >> 6;
    if (lane == 0) { red[w] = s; red[4 + w] = ss; }
    __syncthreads();
    s  = red[0] + red[1] + red[2] + red[3];
    ss = red[4] + red[5] + red[6] + red[7];
    float mu = s * (1.f / 1024.f);
    float var = ss * (1.f / 1024.f) - mu * mu;
    float rstd = rsqrtf(fmaxf(var, 0.f) + 1e-5f);
    float4 gv = ((const float4*)g)[t];
    float4 bv = ((const float4*)bta)[t];
    bf16x4 ov;
    ov[0] = (__bf16)((f[0] - mu) * rstd * gv.x + bv.x);
    ov[1] = (__bf16)((f[1] - mu) * rstd * gv.y + bv.y);
    ov[2] = (__bf16)((f[2] - mu) * rstd * gv.z + bv.z);
    ov[3] = (__bf16)((f[3] - mu) * rstd * gv.w + bv.w);
    ((bf16x4*)(out + (size_t)row * 1024))[t] = ov;
}

// ---------------- GEMM 256x256 8-phase (T3+T4+T5, linear LDS): fat-N layers ----------------
// 512 thr = 8 waves (2Mx4N), BK=64, LDS 128 KiB (2 dbuf x (A 32K + B 32K)).
// Per K-tile: 4 phases, each {ds-read frag subtile | stage half-tile | s_barrier |
// lgkmcnt(0) | 16 MFMA} with counted vmcnt(4) once per tile (never 0 mid-loop).
// Stage schedule: q0:B-khalf0(t+1), q1:B-khalf1(t+1), q3:A(t+2)+vmcnt.
// EPI: 0 bias, 2 bias+gelu; bf16 out.
template <int EPI>
__global__ __launch_bounds__(512, 2) void gemm256_kernel(
    const __bf16* __restrict__ A, const __bf16* __restrict__ BT,
    const float* __restrict__ bias, void* __restrict__ Cp, int M, int N, int K)
{
    __shared__ __align__(16) __bf16 lA[2][256 * 64];  // phys = kc*2048 + row*8 + (k&7)
    __shared__ __align__(16) __bf16 lB[2][256 * 64];
    const int t = threadIdx.x;
    const int lane = t & 63, w = t >> 6;
    const int wm = w >> 2, wn = w & 3;          // wave tile: rows wm*128, cols wn*64
    const int q4 = lane >> 4, r16 = lane & 15;
    const int nwg = gridDim.x * gridDim.y;
    const int nf = xcd_swizzle(blockIdx.y * gridDim.x + blockIdx.x, nwg);
    const int bm = (nf / gridDim.x) * 256, bn = (nf % gridDim.x) * 256;

    const int srow = t & 255;
    const int skc  = t >> 8;                    // 0 or 1
    const __bf16* gA = A  + (size_t)(bm + srow) * K + skc * 8;
    const __bf16* gB = BT + (size_t)(bn + srow) * K + skc * 8;
    const int dst = skc * 2048 + srow * 8;      // LDS elem offset; +j*4096 per gload j

    f32x4 acc[8][4];
    f32x4 zero4 = {0.f, 0.f, 0.f, 0.f};
#pragma unroll
    for (int mi = 0; mi < 8; ++mi)
#pragma unroll
        for (int ni = 0; ni < 4; ++ni) acc[mi][ni] = zero4;

    // prologue: full tile 0 (A+B) and A of tile 1; 12 loads, wait till 8 landed
#pragma unroll
    for (int j = 0; j < 4; ++j) gload16(gA + j * 16, &lA[0][dst + j * 4096]);
#pragma unroll
    for (int j = 0; j < 4; ++j) gload16(gB + j * 16, &lB[0][dst + j * 4096]);
#pragma unroll
    for (int j = 0; j < 4; ++j) gload16(gA + 64 + j * 16, &lA[1][dst + j * 4096]);
    asm volatile("s_waitcnt vmcnt(4)" ::: "memory");
    __builtin_amdgcn_s_barrier();

    const int nt = K / 64;
    for (int ti = 0; ti < nt; ++ti) {
        const int p = ti & 1;
        bf16x8 af[4][2], bfr[2][2];
#pragma unroll
        for (int q = 0; q < 4; ++q) {
            const int qm = q >> 1, qn = q & 1;
            // --- ds-read register subtile for this phase ---
            if (qn == 0) {
#pragma unroll
                for (int mi = 0; mi < 4; ++mi)
#pragma unroll
                    for (int ks = 0; ks < 2; ++ks)
                        af[mi][ks] = *(const bf16x8*)&lA[p][(ks * 4 + q4) * 2048 +
                            (wm * 128 + qm * 64 + mi * 16 + r16) * 8];
            }
#pragma unroll
            for (int ni = 0; ni < 2; ++ni)
#pragma unroll
                for (int ks = 0; ks < 2; ++ks)
                    bfr[ni][ks] = *(const bf16x8*)&lB[p][(ks * 4 + q4) * 2048 +
                        (wn * 64 + qn * 32 + ni * 16 + r16) * 8];
            // --- stage-issue (counted, spans barriers) ---
            if (q == 0 && ti + 1 < nt) {
                gload16(gB + (ti + 1) * 64,      &lB[p ^ 1][dst]);
                gload16(gB + (ti + 1) * 64 + 16, &lB[p ^ 1][dst + 4096]);
            }
            if (q == 1 && ti + 1 < nt) {
                gload16(gB + (ti + 1) * 64 + 32, &lB[p ^ 1][dst + 8192]);
                gload16(gB + (ti + 1) * 64 + 48, &lB[p ^ 1][dst + 12288]);
            }
            if (q == 3) {
                if (ti + 2 < nt) {
#pragma unroll
                    for (int j = 0; j < 4; ++j)
                        gload16(gA + (ti + 2) * 64 + j * 16, &lA[p][dst + j * 4096]);
                    asm volatile("s_waitcnt vmcnt(4)" ::: "memory");
                } else {
                    asm volatile("s_waitcnt vmcnt(0)" ::: "memory");
                }
            }
            __builtin_amdgcn_s_barrier();
            asm volatile("s_waitcnt lgkmcnt(0)" ::: "memory");
            __builtin_amdgcn_sched_barrier(0);
            __builtin_amdgcn_s_setprio(1);
#pragma unroll
            for (int mi = 0; mi < 4; ++mi)
#pragma unroll
                for (int ni = 0; ni < 2; ++ni) {
                    f32x4 v = acc[qm * 4 + mi][qn * 2 + ni];
                    v = __builtin_amdgcn_mfma_f32_16x16x32_bf16(af[mi][0], bfr[ni][0], v, 0, 0, 0);
                    v = __builtin_amdgcn_mfma_f32_16x16x32_bf16(af[mi][1], bfr[ni][1], v, 0, 0, 0);
                    acc[qm * 4 + mi][qn * 2 + ni] = v;
                }
            __builtin_amdgcn_s_setprio(0);
            __builtin_amdgcn_sched_barrier(0);
            __builtin_amdgcn_s_barrier();
        }
    }

    // epilogue
#pragma unroll
    for (int mi = 0; mi < 8; ++mi) {
#pragma unroll
        for (int ni = 0; ni < 4; ++ni) {
#pragma unroll
            for (int i = 0; i < 4; ++i) {
                int r = bm + wm * 128 + mi * 16 + q4 * 4 + i;
                int c = bn + wn * 64 + ni * 16 + r16;
                float v = acc[mi][ni][i] + bias[c];
                if (EPI == 2) v = gelu_f(v);
                ((__bf16*)Cp)[(size_t)r * N + c] = (__bf16)v;
            }
        }
    }
}

// ---------------- GEMM 128x128 (dbuf 2-phase + XCD swizzle): skinny-N layers ----------------
// EPI: 0 bias, 1 bias+res(f32), 2 bias+gelu
template <int EPI, bool OUT32>
__global__ __launch_bounds__(256, 4) void gemm_bt_kernel(
    const __bf16* __restrict__ A, const __bf16* __restrict__ BT,
    const float* __restrict__ bias, const float* __restrict__ res,
    void* __restrict__ Cp, int M, int N, int K)
{
    __shared__ __align__(16) __bf16 lA[2][BM * BK];
    __shared__ __align__(16) __bf16 lB[2][BN * BK];
    const int t = threadIdx.x;
    const int lane = t & 63;
    const int wave = t >> 6;
    const int wm = wave >> 1, wn = wave & 1;
    const int q4 = lane >> 4, r16 = lane & 15;
    const int nwg = gridDim.x * gridDim.y;
    const int nf = xcd_swizzle(blockIdx.y * gridDim.x + blockIdx.x, nwg);
    const int bm = (nf / gridDim.x) * BM, bn = (nf % gridDim.x) * BN;

    const int srow = t & 127;
    const int skc = t >> 7;
    const __bf16* ga0 = A + (size_t)(bm + srow) * K + skc * 8;
    const __bf16* ga1 = ga0 + 16;
    const __bf16* gb0 = BT + (size_t)(bn + srow) * K + skc * 8;
    const __bf16* gb1 = gb0 + 16;

    f32x4 acc[4][4];
    f32x4 zero4 = {0.f, 0.f, 0.f, 0.f};
#pragma unroll
    for (int mi = 0; mi < 4; ++mi)
#pragma unroll
        for (int ni = 0; ni < 4; ++ni) acc[mi][ni] = zero4;

    gload16(ga0, &lA[0][t * 8]);
    gload16(ga1, &lA[0][t * 8 + 2048]);
    gload16(gb0, &lB[0][t * 8]);
    gload16(gb1, &lB[0][t * 8 + 2048]);
    ga0 += BK; ga1 += BK; gb0 += BK; gb1 += BK;
    __syncthreads();

    const int nk = K / BK;
    int cur = 0;
    for (int it = 0; it < nk; ++it) {
        if (it + 1 < nk) {
            gload16(ga0, &lA[cur ^ 1][t * 8]);
            gload16(ga1, &lA[cur ^ 1][t * 8 + 2048]);
            gload16(gb0, &lB[cur ^ 1][t * 8]);
            gload16(gb1, &lB[cur ^ 1][t * 8 + 2048]);
            ga0 += BK; ga1 += BK; gb0 += BK; gb1 += BK;
        }
        bf16x8 af[4], bfr[4];
#pragma unroll
        for (int i = 0; i < 4; ++i)
            af[i] = *(const bf16x8*)&lA[cur][q4 * 1024 + (wm * 64 + i * 16 + r16) * 8];
#pragma unroll
        for (int i = 0; i < 4; ++i)
            bfr[i] = *(const bf16x8*)&lB[cur][q4 * 1024 + (wn * 64 + i * 16 + r16) * 8];
#pragma unroll
        for (int mi = 0; mi < 4; ++mi)
#pragma unroll
            for (int ni = 0; ni < 4; ++ni)
                acc[mi][ni] = __builtin_amdgcn_mfma_f32_16x16x32_bf16(
                    af[mi], bfr[ni], acc[mi][ni], 0, 0, 0);
        if (it + 1 < nk) __syncthreads();
        cur ^= 1;
    }

#pragma unroll
    for (int mi = 0; mi < 4; ++mi) {
#pragma unroll
        for (int ni = 0; ni < 4; ++ni) {
#pragma unroll
            for (int i = 0; i < 4; ++i) {
                int r = bm + wm * 64 + mi * 16 + q4 * 4 + i;
                int c = bn + wn * 64 + ni * 16 + r16;
                float v = acc[mi][ni][i] + bias[c];
                if (EPI == 1) v += res[(size_t)r * N + c];
                if (EPI == 2) v = gelu_f(v);
                if (OUT32) ((float*)Cp)[(size_t)r * N + c] = v;
                else       ((__bf16*)Cp)[(size_t)r * N + c] = (__bf16)v;
            }
        }
    }
}

// ---------------- Flash attention (causal), HD=64, T=2048, NH=16 ----------------
__global__ __launch_bounds__(256, 4) void attn_kernel(
    const __bf16* __restrict__ qkv, __bf16* __restrict__ attnb)
{
    __shared__ __align__(16) __bf16 lK[8192];
    __shared__ __align__(16) __bf16 lV[8192];
    __shared__ __align__(16) __bf16 lP[4][512];

    const int t = threadIdx.x, lane = t & 63, w = t >> 6;
    const int q4 = lane >> 4, r16 = lane & 15;
    const int nf = xcd_swizzle(blockIdx.y * 16 + blockIdx.x, 1024);
    const int qt = nf & 15;
    const int bh = nf >> 4;
    const int b = bh >> 4, h = bh & 15;
    const int qb = qt * 128;
    const __bf16* Qb = qkv + (size_t)b * 2048 * 3072 + h * 64;
    const __bf16* Kb = Qb + 1024;
    const __bf16* Vb = Qb + 2048;

    bf16x8 qf[2][2];
#pragma unroll
    for (int p = 0; p < 2; ++p) {
        int qrow = qb + p * 64 + w * 16 + r16;
        qf[p][0] = *(const bf16x8*)(Qb + (size_t)qrow * 3072 + q4 * 8);
        qf[p][1] = *(const bf16x8*)(Qb + (size_t)qrow * 3072 + 32 + q4 * 8);
#pragma unroll
        for (int j = 0; j < 8; ++j) {
            qf[p][0][j] = (__bf16)((float)qf[p][0][j] * 0.125f);
            qf[p][1][j] = (__bf16)((float)qf[p][1][j] * 0.125f);
        }
    }

    f32x4 zero4 = {0.f, 0.f, 0.f, 0.f};
    f32x4 o[2][4];
    float rs[2][4];
#pragma unroll
    for (int p = 0; p < 2; ++p)
#pragma unroll
        for (int i = 0; i < 4; ++i) { o[p][i] = zero4; rs[p][i] = 0.f; }

    const int skey = t & 127;
    const int vkc = t >> 6, svd = t & 63;

    for (int kb = 0; kb < qb + 128; kb += 128) {
        __syncthreads();
#pragma unroll
        for (int c = 0; c < 4; ++c)
            gload16(Kb + (size_t)(kb + skey) * 3072 + (c * 2 + (t >> 7)) * 8,
                    &lK[c * 2048 + t * 8]);
#pragma unroll
        for (int c = 0; c < 4; ++c) {
            int kc = c * 4 + vkc;
            bf16x8 vt;
#pragma unroll
            for (int j = 0; j < 8; ++j)
                vt[j] = Vb[(size_t)(kb + kc * 8 + j) * 3072 + svd];
            *(bf16x8*)&lV[kc * 512 + svd * 8] = vt;
        }
        __syncthreads();

#pragma unroll
        for (int p = 0; p < 2; ++p) {
            const int row0 = qb + p * 64 + w * 16 + q4 * 4;
            const bool interior = (kb + 127) <= (qb + p * 64 + w * 16);

            f32x4 s[8];
#pragma unroll
            for (int kg = 0; kg < 8; ++kg) {
                bf16x8 kfA = *(const bf16x8*)&lK[q4 * 1024 + (kg * 16 + r16) * 8];
                bf16x8 kfB = *(const bf16x8*)&lK[(4 + q4) * 1024 + (kg * 16 + r16) * 8];
                s[kg] = __builtin_amdgcn_mfma_f32_16x16x32_bf16(qf[p][0], kfA, zero4, 0, 0, 0);
                s[kg] = __builtin_amdgcn_mfma_f32_16x16x32_bf16(qf[p][1], kfB, s[kg], 0, 0, 0);
            }

#pragma unroll
            for (int kg = 0; kg < 8; ++kg)
#pragma unroll
                for (int i = 0; i < 4; ++i) {
                    float e = __expf(fminf(s[kg][i], 75.f));
                    if (!interior && (kb + kg * 16 + r16) > (row0 + i)) e = 0.f;
                    s[kg][i] = e;
                    rs[p][i] += e;
                }

#pragma unroll
            for (int c = 0; c < 4; ++c) {
#pragma unroll
                for (int kh = 0; kh < 2; ++kh)
#pragma unroll
                    for (int i = 0; i < 4; ++i)
                        lP[w][(kh * 2 + (r16 >> 3)) * 128 + (q4 * 4 + i) * 8 + (r16 & 7)] =
                            (__bf16)s[c * 2 + kh][i];
                asm volatile("s_waitcnt lgkmcnt(0)" ::: "memory");
                bf16x8 pf = *(const bf16x8*)&lP[w][q4 * 128 + r16 * 8];
#pragma unroll
                for (int ci = 0; ci < 4; ++ci) {
                    bf16x8 vf = *(const bf16x8*)&lV[(c * 4 + q4) * 512 + (ci * 16 + r16) * 8];
                    o[p][ci] = __builtin_amdgcn_mfma_f32_16x16x32_bf16(pf, vf, o[p][ci], 0, 0, 0);
                }
            }
        }
    }

#pragma unroll
    for (int p = 0; p < 2; ++p) {
#pragma unroll
        for (int off = 8; off; off >>= 1)
#pragma unroll
            for (int i = 0; i < 4; ++i) rs[p][i] += __shfl_xor(rs[p][i], off, 64);
#pragma unroll
        for (int ci = 0; ci < 4; ++ci)
#pragma unroll
            for (int i = 0; i < 4; ++i) {
                int trow = qb + p * 64 + w * 16 + q4 * 4 + i;
                float inv_l = (rs[p][i] > 0.f) ? (1.f / rs[p][i]) : 0.f;
                attnb[(size_t)(b * 2048 + trow) * 1024 + h * 64 + ci * 16 + r16] =
                    (__bf16)(o[p][ci][i] * inv_l);
            }
    }
}

// ---------------- launcher ----------------
extern "C" void kernel_launch(void* const* d_in, const int* in_sizes, int n_in,
                              void* d_out, int out_size, void* d_ws, size_t ws_size,
                              hipStream_t stream)
{
    const float* x      = (const float*)d_in[0];
    const float* ln1_g  = (const float*)d_in[1];
    const float* ln1_b  = (const float*)d_in[2];
    const float* w_qkv  = (const float*)d_in[3];
    const float* b_qkv  = (const float*)d_in[4];
    const float* w_proj = (const float*)d_in[5];
    const float* b_proj = (const float*)d_in[6];
    const float* ln2_g  = (const float*)d_in[7];
    const float* ln2_b  = (const float*)d_in[8];
    const float* w_fc   = (const float*)d_in[9];
    const float* b_fc   = (const float*)d_in[10];
    const float* w_mlp  = (const float*)d_in[11];
    const float* b_mlp  = (const float*)d_in[12];
    float* out = (float*)d_out;

    const size_t MiB = (size_t)1 << 20;
    if (ws_size < 136 * MiB) {
        float v = 1000.f + (float)(ws_size >> 20);
        diag_kernel<<<(out_size + 255) / 256, 256, 0, stream>>>(out, out_size, v);
        return;
    }

    char* ws = (char*)d_ws;
    __bf16* bufA   = (__bf16*)(ws);              // 16 MiB: h -> attnb -> h2
    __bf16* bufB   = (__bf16*)(ws + 16 * MiB);   // 64 MiB: qkvb(48) -> ffb(64)
    float*  x1     = (float*) (ws + 80 * MiB);   // 32 MiB fp32 residual
    __bf16* wqkvT  = (__bf16*)(ws + 112 * MiB);  // 6 MiB
    __bf16* wprojT = (__bf16*)(ws + 118 * MiB);  // 2 MiB
    __bf16* wfcT   = (__bf16*)(ws + 120 * MiB);  // 8 MiB
    __bf16* wmlpT  = (__bf16*)(ws + 128 * MiB);  // 8 MiB

    cvtT_kernel<<<dim3(96, 32),  256, 0, stream>>>(w_qkv,  wqkvT,  1024, 3072);
    cvtT_kernel<<<dim3(32, 32),  256, 0, stream>>>(w_proj, wprojT, 1024, 1024);
    cvtT_kernel<<<dim3(128, 32), 256, 0, stream>>>(w_fc,   wfcT,   1024, 4096);
    cvtT_kernel<<<dim3(32, 128), 256, 0, stream>>>(w_mlp,  wmlpT,  4096, 1024);

    ln_kernel<<<8192, 256, 0, stream>>>(x, ln1_g, ln1_b, bufA);
    gemm256_kernel<0><<<dim3(12, 32), 512, 0, stream>>>(
        bufA, wqkvT, b_qkv, bufB, 8192, 3072, 1024);
    attn_kernel<<<dim3(16, 64), 256, 0, stream>>>(bufB, bufA);
    gemm_bt_kernel<1, true><<<dim3(8, 64), 256, 0, stream>>>(
        bufA, wprojT, b_proj, x, x1, 8192, 1024, 1024);
    ln_kernel<<<8192, 256, 0, stream>>>(x1, ln2_g, ln2_b, bufA);
    gemm256_kernel<2><<<dim3(16, 32), 512, 0, stream>>>(
        bufA, wfcT, b_fc, bufB, 8192, 4096, 1024);
    gemm_bt_kernel<1, true><<<dim3(8, 64), 256, 0, stream>>>(
        bufB, wmlpT, b_mlp, x1, out, 8192, 1024, 4096);
}

// Round 5
// 680.119 us; speedup vs baseline: 1.0680x; 1.0099x over previous
//
#include <hip/hip_runtime.h>
#include <hip/hip_bf16.h>

typedef __bf16 bf16x8 __attribute__((ext_vector_type(8)));
typedef __bf16 bf16x4 __attribute__((ext_vector_type(4)));
typedef float f32x4 __attribute__((ext_vector_type(4)));

__device__ __forceinline__ void gload16(const __bf16* g, __bf16* l) {
    __builtin_amdgcn_global_load_lds((const __attribute__((address_space(1))) void*)g,
                                     (__attribute__((address_space(3))) void*)l, 16, 0, 0);
}

__device__ __forceinline__ float gelu_f(float v) {
    float z = 0.7978845608028654f * (v + 0.044715f * v * v * v);
    float e = __expf(2.f * z);
    return 0.5f * v * (2.f - 2.f / (e + 1.f));  // 0.5*v*(1+tanh(z)), overflow-safe
}

// XCD-chunk swizzle (bijective when nwg%8==0)
__device__ __forceinline__ int xcd_swizzle(int flat, int nwg) {
    return (flat & 7) * (nwg >> 3) + (flat >> 3);
}

// ---------------- diagnostic fill (fp32 out) ----------------
__global__ __launch_bounds__(256) void diag_kernel(float* out, int n, float v) {
    int i = blockIdx.x * 256 + threadIdx.x;
    if (i < n) out[i] = v;
}

// ---------------- fused fp32->bf16 convert + transpose: in[K,N] -> out[N,K] ----------------
__global__ __launch_bounds__(256) void cvtT_kernel(
    const float* __restrict__ in, __bf16* __restrict__ out, int K, int N)
{
    __shared__ __bf16 tile[32][33];
    int bx = blockIdx.x * 32, by = blockIdx.y * 32;
    int tx = threadIdx.x & 31, ty = threadIdx.x >> 5;
#pragma unroll
    for (int i = 0; i < 32; i += 8)
        tile[ty + i][tx] = (__bf16)in[(size_t)(by + ty + i) * N + bx + tx];
    __syncthreads();
#pragma unroll
    for (int i = 0; i < 32; i += 8)
        out[(size_t)(bx + ty + i) * K + by + tx] = tile[tx][ty + i];
}

// ---------------- LayerNorm: fp32 in, bf16 out ----------------
__global__ __launch_bounds__(256) void ln_kernel(
    const float* __restrict__ x, const float* __restrict__ g,
    const float* __restrict__ bta, __bf16* __restrict__ out)
{
    const int row = blockIdx.x, t = threadIdx.x;
    const float* xr = x + (size_t)row * 1024;
    float4 xv = ((const float4*)xr)[t];
    float f[4] = {xv.x, xv.y, xv.z, xv.w};
    float s = f[0] + f[1] + f[2] + f[3];
    float ss = f[0]*f[0] + f[1]*f[1] + f[2]*f[2] + f[3]*f[3];
#pragma unroll
    for (int off = 32; off; off >>= 1) {
        s  += __shfl_xor(s, off, 64);
        ss += __shfl_xor(ss, off, 64);
    }
    __shared__ float red[8];
    int lane = t & 63, w = t >> 6;
    if (lane == 0) { red[w] = s; red[4 + w] = ss; }
    __syncthreads();
    s  = red[0] + red[1] + red[2] + red[3];
    ss = red[4] + red[5] + red[6] + red[7];
    float mu = s * (1.f / 1024.f);
    float var = ss * (1.f / 1024.f) - mu * mu;
    float rstd = rsqrtf(fmaxf(var, 0.f) + 1e-5f);
    float4 gv = ((const float4*)g)[t];
    float4 bv = ((const float4*)bta)[t];
    bf16x4 ov;
    ov[0] = (__bf16)((f[0] - mu) * rstd * gv.x + bv.x);
    ov[1] = (__bf16)((f[1] - mu) * rstd * gv.y + bv.y);
    ov[2] = (__bf16)((f[2] - mu) * rstd * gv.z + bv.z);
    ov[3] = (__bf16)((f[3] - mu) * rstd * gv.w + bv.w);
    ((bf16x4*)(out + (size_t)row * 1024))[t] = ov;
}

// ---------------- GEMM 256x256 8-phase (T3+T4+T5, linear LDS): fat-N layers ----------------
// 512 thr = 8 waves (2Mx4N), BK=64, LDS 128 KiB. Counted vmcnt(4), never 0 mid-loop.
// EPI: 0 bias, 2 bias+gelu; bf16 out.
template <int EPI>
__global__ __launch_bounds__(512, 2) void gemm256_kernel(
    const __bf16* __restrict__ A, const __bf16* __restrict__ BT,
    const float* __restrict__ bias, void* __restrict__ Cp, int M, int N, int K)
{
    __shared__ __align__(16) __bf16 lA[2][256 * 64];  // phys = kg*2048 + row*8 + (k&7)
    __shared__ __align__(16) __bf16 lB[2][256 * 64];
    const int t = threadIdx.x;
    const int lane = t & 63, w = t >> 6;
    const int wm = w >> 2, wn = w & 3;          // wave tile: rows wm*128, cols wn*64
    const int q4 = lane >> 4, r16 = lane & 15;
    const int nwg = gridDim.x * gridDim.y;
    const int nf = xcd_swizzle(blockIdx.y * gridDim.x + blockIdx.x, nwg);
    const int bm = (nf / gridDim.x) * 256, bn = (nf % gridDim.x) * 256;

    const int srow = t & 255;
    const int skc  = t >> 8;                    // 0 or 1
    const __bf16* gA = A  + (size_t)(bm + srow) * K + skc * 8;
    const __bf16* gB = BT + (size_t)(bn + srow) * K + skc * 8;
    const int dst = skc * 2048 + srow * 8;      // +j*4096 per gload j

    f32x4 acc[8][4];
    f32x4 zero4 = {0.f, 0.f, 0.f, 0.f};
#pragma unroll
    for (int mi = 0; mi < 8; ++mi)
#pragma unroll
        for (int ni = 0; ni < 4; ++ni) acc[mi][ni] = zero4;

    // prologue: tile0 (A+B) + tile1 A; 12 loads, wait till first 8 landed
#pragma unroll
    for (int j = 0; j < 4; ++j) gload16(gA + j * 16, &lA[0][dst + j * 4096]);
#pragma unroll
    for (int j = 0; j < 4; ++j) gload16(gB + j * 16, &lB[0][dst + j * 4096]);
#pragma unroll
    for (int j = 0; j < 4; ++j) gload16(gA + 64 + j * 16, &lA[1][dst + j * 4096]);
    asm volatile("s_waitcnt vmcnt(4)" ::: "memory");
    __builtin_amdgcn_s_barrier();

    const int nt = K / 64;
    for (int ti = 0; ti < nt; ++ti) {
        const int p = ti & 1;
        bf16x8 af[4][2], bfr[2][2];
#pragma unroll
        for (int q = 0; q < 4; ++q) {
            const int qm = q >> 1, qn = q & 1;
            if (qn == 0) {
#pragma unroll
                for (int mi = 0; mi < 4; ++mi)
#pragma unroll
                    for (int ks = 0; ks < 2; ++ks)
                        af[mi][ks] = *(const bf16x8*)&lA[p][(ks * 4 + q4) * 2048 +
                            (wm * 128 + qm * 64 + mi * 16 + r16) * 8];
            }
#pragma unroll
            for (int ni = 0; ni < 2; ++ni)
#pragma unroll
                for (int ks = 0; ks < 2; ++ks)
                    bfr[ni][ks] = *(const bf16x8*)&lB[p][(ks * 4 + q4) * 2048 +
                        (wn * 64 + qn * 32 + ni * 16 + r16) * 8];
            if (q == 0 && ti + 1 < nt) {
                gload16(gB + (ti + 1) * 64,      &lB[p ^ 1][dst]);
                gload16(gB + (ti + 1) * 64 + 16, &lB[p ^ 1][dst + 4096]);
            }
            if (q == 1 && ti + 1 < nt) {
                gload16(gB + (ti + 1) * 64 + 32, &lB[p ^ 1][dst + 8192]);
                gload16(gB + (ti + 1) * 64 + 48, &lB[p ^ 1][dst + 12288]);
            }
            if (q == 3) {
                if (ti + 2 < nt) {
#pragma unroll
                    for (int j = 0; j < 4; ++j)
                        gload16(gA + (ti + 2) * 64 + j * 16, &lA[p][dst + j * 4096]);
                    asm volatile("s_waitcnt vmcnt(4)" ::: "memory");
                } else {
                    asm volatile("s_waitcnt vmcnt(0)" ::: "memory");
                }
            }
            __builtin_amdgcn_s_barrier();
            asm volatile("s_waitcnt lgkmcnt(0)" ::: "memory");
            __builtin_amdgcn_sched_barrier(0);
            __builtin_amdgcn_s_setprio(1);
#pragma unroll
            for (int mi = 0; mi < 4; ++mi)
#pragma unroll
                for (int ni = 0; ni < 2; ++ni) {
                    f32x4 v = acc[qm * 4 + mi][qn * 2 + ni];
                    v = __builtin_amdgcn_mfma_f32_16x16x32_bf16(af[mi][0], bfr[ni][0], v, 0, 0, 0);
                    v = __builtin_amdgcn_mfma_f32_16x16x32_bf16(af[mi][1], bfr[ni][1], v, 0, 0, 0);
                    acc[qm * 4 + mi][qn * 2 + ni] = v;
                }
            __builtin_amdgcn_s_setprio(0);
            __builtin_amdgcn_sched_barrier(0);
            __builtin_amdgcn_s_barrier();
        }
    }

#pragma unroll
    for (int mi = 0; mi < 8; ++mi) {
#pragma unroll
        for (int ni = 0; ni < 4; ++ni) {
#pragma unroll
            for (int i = 0; i < 4; ++i) {
                int r = bm + wm * 128 + mi * 16 + q4 * 4 + i;
                int c = bn + wn * 64 + ni * 16 + r16;
                float v = acc[mi][ni][i] + bias[c];
                if (EPI == 2) v = gelu_f(v);
                ((__bf16*)Cp)[(size_t)r * N + c] = (__bf16)v;
            }
        }
    }
}

// ---------------- GEMM 128x256 8-phase: skinny-N layers (proj, mlp_proj) ----------------
// Same schedule as gemm256 with swapped tile aspect: BM=128, BN=256, 8 waves (2Mx4N),
// wave tile 64x64, BK=64, LDS 96 KiB (A 2x16K, B 2x32K) -> grid (N/256, M/128) = 256
// blocks = 1/CU for N=1024. Counted vmcnt(2). Epilogue: bias + fp32 residual, fp32 out.
template <int EPI>   // 1: bias+res
__global__ __launch_bounds__(512, 2) void gemm128x256_kernel(
    const __bf16* __restrict__ A, const __bf16* __restrict__ BT,
    const float* __restrict__ bias, const float* __restrict__ res,
    float* __restrict__ C, int M, int N, int K)
{
    __shared__ __align__(16) __bf16 lA[2][128 * 64];  // phys = kg*1024 + row*8 + (k&7)
    __shared__ __align__(16) __bf16 lB[2][256 * 64];  // phys = kg*2048 + col*8 + (k&7)
    const int t = threadIdx.x;
    const int lane = t & 63, w = t >> 6;
    const int wm = w >> 2, wn = w & 3;          // wave tile: rows wm*64, cols wn*64
    const int q4 = lane >> 4, r16 = lane & 15;
    const int nwg = gridDim.x * gridDim.y;
    const int nf = xcd_swizzle(blockIdx.y * gridDim.x + blockIdx.x, nwg);
    const int bm = (nf / gridDim.x) * 128, bn = (nf % gridDim.x) * 256;

    // A staging: 128 rows x 64 k = 2 gloads; thread -> (row = t&127, kq = t>>7)
    const int srA = t & 127, kqA = t >> 7;      // kqA in 0..3
    const __bf16* gA = A + (size_t)(bm + srA) * K + kqA * 8;
    const int dstA = kqA * 1024 + srA * 8;      // +j*4096 per gload j (kg += 4)
    // B staging: 256 rows x 64 k = 4 gloads; thread -> (row = t&255, sk = t>>8)
    const int srB = t & 255, skB = t >> 8;      // skB in 0..1
    const __bf16* gB = BT + (size_t)(bn + srB) * K + skB * 8;
    const int dstB = skB * 2048 + srB * 8;      // +j*4096 per gload j (kg += 2)

    f32x4 acc[4][4];
    f32x4 zero4 = {0.f, 0.f, 0.f, 0.f};
#pragma unroll
    for (int mi = 0; mi < 4; ++mi)
#pragma unroll
        for (int ni = 0; ni < 4; ++ni) acc[mi][ni] = zero4;

    // prologue: tile0 (A 2 + B 4) + tile1 A 2; wait till first 6 landed
#pragma unroll
    for (int j = 0; j < 2; ++j) gload16(gA + j * 32, &lA[0][dstA + j * 4096]);
#pragma unroll
    for (int j = 0; j < 4; ++j) gload16(gB + j * 16, &lB[0][dstB + j * 4096]);
#pragma unroll
    for (int j = 0; j < 2; ++j) gload16(gA + 64 + j * 32, &lA[1][dstA + j * 4096]);
    asm volatile("s_waitcnt vmcnt(2)" ::: "memory");
    __builtin_amdgcn_s_barrier();

    const int nt = K / 64;
    for (int ti = 0; ti < nt; ++ti) {
        const int p = ti & 1;
        bf16x8 af[2][2], bfr[2][2];
#pragma unroll
        for (int q = 0; q < 4; ++q) {
            const int qm = q >> 1, qn = q & 1;
            if (qn == 0) {
#pragma unroll
                for (int mi = 0; mi < 2; ++mi)
#pragma unroll
                    for (int ks = 0; ks < 2; ++ks)
                        af[mi][ks] = *(const bf16x8*)&lA[p][(ks * 4 + q4) * 1024 +
                            (wm * 64 + qm * 32 + mi * 16 + r16) * 8];
            }
#pragma unroll
            for (int ni = 0; ni < 2; ++ni)
#pragma unroll
                for (int ks = 0; ks < 2; ++ks)
                    bfr[ni][ks] = *(const bf16x8*)&lB[p][(ks * 4 + q4) * 2048 +
                        (wn * 64 + qn * 32 + ni * 16 + r16) * 8];
            if (q == 0 && ti + 1 < nt) {
                gload16(gB + (ti + 1) * 64,      &lB[p ^ 1][dstB]);
                gload16(gB + (ti + 1) * 64 + 16, &lB[p ^ 1][dstB + 4096]);
            }
            if (q == 1 && ti + 1 < nt) {
                gload16(gB + (ti + 1) * 64 + 32, &lB[p ^ 1][dstB + 8192]);
                gload16(gB + (ti + 1) * 64 + 48, &lB[p ^ 1][dstB + 12288]);
            }
            if (q == 3) {
                if (ti + 2 < nt) {
#pragma unroll
                    for (int j = 0; j < 2; ++j)
                        gload16(gA + (ti + 2) * 64 + j * 32, &lA[p][dstA + j * 4096]);
                    asm volatile("s_waitcnt vmcnt(2)" ::: "memory");
                } else {
                    asm volatile("s_waitcnt vmcnt(0)" ::: "memory");
                }
            }
            __builtin_amdgcn_s_barrier();
            asm volatile("s_waitcnt lgkmcnt(0)" ::: "memory");
            __builtin_amdgcn_sched_barrier(0);
            __builtin_amdgcn_s_setprio(1);
#pragma unroll
            for (int mi = 0; mi < 2; ++mi)
#pragma unroll
                for (int ni = 0; ni < 2; ++ni) {
                    f32x4 v = acc[qm * 2 + mi][qn * 2 + ni];
                    v = __builtin_amdgcn_mfma_f32_16x16x32_bf16(af[mi][0], bfr[ni][0], v, 0, 0, 0);
                    v = __builtin_amdgcn_mfma_f32_16x16x32_bf16(af[mi][1], bfr[ni][1], v, 0, 0, 0);
                    acc[qm * 2 + mi][qn * 2 + ni] = v;
                }
            __builtin_amdgcn_s_setprio(0);
            __builtin_amdgcn_sched_barrier(0);
            __builtin_amdgcn_s_barrier();
        }
    }

#pragma unroll
    for (int mi = 0; mi < 4; ++mi) {
#pragma unroll
        for (int ni = 0; ni < 4; ++ni) {
#pragma unroll
            for (int i = 0; i < 4; ++i) {
                int r = bm + wm * 64 + mi * 16 + q4 * 4 + i;
                int c = bn + wn * 64 + ni * 16 + r16;
                float v = acc[mi][ni][i] + bias[c];
                if (EPI == 1) v += res[(size_t)r * N + c];
                C[(size_t)r * N + c] = v;
            }
        }
    }
}

// ---------------- Flash attention (causal), HD=64, T=2048, NH=16 ----------------
__global__ __launch_bounds__(256, 4) void attn_kernel(
    const __bf16* __restrict__ qkv, __bf16* __restrict__ attnb)
{
    __shared__ __align__(16) __bf16 lK[8192];
    __shared__ __align__(16) __bf16 lV[8192];
    __shared__ __align__(16) __bf16 lP[4][512];

    const int t = threadIdx.x, lane = t & 63, w = t >> 6;
    const int q4 = lane >> 4, r16 = lane & 15;
    const int nf = xcd_swizzle(blockIdx.y * 16 + blockIdx.x, 1024);
    const int qt = nf & 15;
    const int bh = nf >> 4;
    const int b = bh >> 4, h = bh & 15;
    const int qb = qt * 128;
    const __bf16* Qb = qkv + (size_t)b * 2048 * 3072 + h * 64;
    const __bf16* Kb = Qb + 1024;
    const __bf16* Vb = Qb + 2048;

    bf16x8 qf[2][2];
#pragma unroll
    for (int p = 0; p < 2; ++p) {
        int qrow = qb + p * 64 + w * 16 + r16;
        qf[p][0] = *(const bf16x8*)(Qb + (size_t)qrow * 3072 + q4 * 8);
        qf[p][1] = *(const bf16x8*)(Qb + (size_t)qrow * 3072 + 32 + q4 * 8);
#pragma unroll
        for (int j = 0; j < 8; ++j) {
            qf[p][0][j] = (__bf16)((float)qf[p][0][j] * 0.125f);
            qf[p][1][j] = (__bf16)((float)qf[p][1][j] * 0.125f);
        }
    }

    f32x4 zero4 = {0.f, 0.f, 0.f, 0.f};
    f32x4 o[2][4];
    float rs[2][4];
#pragma unroll
    for (int p = 0; p < 2; ++p)
#pragma unroll
        for (int i = 0; i < 4; ++i) { o[p][i] = zero4; rs[p][i] = 0.f; }

    const int skey = t & 127;
    const int vkc = t >> 6, svd = t & 63;

    for (int kb = 0; kb < qb + 128; kb += 128) {
        __syncthreads();
#pragma unroll
        for (int c = 0; c < 4; ++c)
            gload16(Kb + (size_t)(kb + skey) * 3072 + (c * 2 + (t >> 7)) * 8,
                    &lK[c * 2048 + t * 8]);
#pragma unroll
        for (int c = 0; c < 4; ++c) {
            int kc = c * 4 + vkc;
            bf16x8 vt;
#pragma unroll
            for (int j = 0; j < 8; ++j)
                vt[j] = Vb[(size_t)(kb + kc * 8 + j) * 3072 + svd];
            *(bf16x8*)&lV[kc * 512 + svd * 8] = vt;
        }
        __syncthreads();

#pragma unroll
        for (int p = 0; p < 2; ++p) {
            const int row0 = qb + p * 64 + w * 16 + q4 * 4;
            const bool interior = (kb + 127) <= (qb + p * 64 + w * 16);

            f32x4 s[8];
#pragma unroll
            for (int kg = 0; kg < 8; ++kg) {
                bf16x8 kfA = *(const bf16x8*)&lK[q4 * 1024 + (kg * 16 + r16) * 8];
                bf16x8 kfB = *(const bf16x8*)&lK[(4 + q4) * 1024 + (kg * 16 + r16) * 8];
                s[kg] = __builtin_amdgcn_mfma_f32_16x16x32_bf16(qf[p][0], kfA, zero4, 0, 0, 0);
                s[kg] = __builtin_amdgcn_mfma_f32_16x16x32_bf16(qf[p][1], kfB, s[kg], 0, 0, 0);
            }

#pragma unroll
            for (int kg = 0; kg < 8; ++kg)
#pragma unroll
                for (int i = 0; i < 4; ++i) {
                    float e = __expf(fminf(s[kg][i], 75.f));
                    if (!interior && (kb + kg * 16 + r16) > (row0 + i)) e = 0.f;
                    s[kg][i] = e;
                    rs[p][i] += e;
                }

#pragma unroll
            for (int c = 0; c < 4; ++c) {
#pragma unroll
                for (int kh = 0; kh < 2; ++kh)
#pragma unroll
                    for (int i = 0; i < 4; ++i)
                        lP[w][(kh * 2 + (r16 >> 3)) * 128 + (q4 * 4 + i) * 8 + (r16 & 7)] =
                            (__bf16)s[c * 2 + kh][i];
                asm volatile("s_waitcnt lgkmcnt(0)" ::: "memory");
                bf16x8 pf = *(const bf16x8*)&lP[w][q4 * 128 + r16 * 8];
#pragma unroll
                for (int ci = 0; ci < 4; ++ci) {
                    bf16x8 vf = *(const bf16x8*)&lV[(c * 4 + q4) * 512 + (ci * 16 + r16) * 8];
                    o[p][ci] = __builtin_amdgcn_mfma_f32_16x16x32_bf16(pf, vf, o[p][ci], 0, 0, 0);
                }
            }
        }
    }

#pragma unroll
    for (int p = 0; p < 2; ++p) {
#pragma unroll
        for (int off = 8; off; off >>= 1)
#pragma unroll
            for (int i = 0; i < 4; ++i) rs[p][i] += __shfl_xor(rs[p][i], off, 64);
#pragma unroll
        for (int ci = 0; ci < 4; ++ci)
#pragma unroll
            for (int i = 0; i < 4; ++i) {
                int trow = qb + p * 64 + w * 16 + q4 * 4 + i;
                float inv_l = (rs[p][i] > 0.f) ? (1.f / rs[p][i]) : 0.f;
                attnb[(size_t)(b * 2048 + trow) * 1024 + h * 64 + ci * 16 + r16] =
                    (__bf16)(o[p][ci][i] * inv_l);
            }
    }
}

// ---------------- launcher ----------------
extern "C" void kernel_launch(void* const* d_in, const int* in_sizes, int n_in,
                              void* d_out, int out_size, void* d_ws, size_t ws_size,
                              hipStream_t stream)
{
    const float* x      = (const float*)d_in[0];
    const float* ln1_g  = (const float*)d_in[1];
    const float* ln1_b  = (const float*)d_in[2];
    const float* w_qkv  = (const float*)d_in[3];
    const float* b_qkv  = (const float*)d_in[4];
    const float* w_proj = (const float*)d_in[5];
    const float* b_proj = (const float*)d_in[6];
    const float* ln2_g  = (const float*)d_in[7];
    const float* ln2_b  = (const float*)d_in[8];
    const float* w_fc   = (const float*)d_in[9];
    const float* b_fc   = (const float*)d_in[10];
    const float* w_mlp  = (const float*)d_in[11];
    const float* b_mlp  = (const float*)d_in[12];
    float* out = (float*)d_out;

    const size_t MiB = (size_t)1 << 20;
    if (ws_size < 136 * MiB) {
        float v = 1000.f + (float)(ws_size >> 20);
        diag_kernel<<<(out_size + 255) / 256, 256, 0, stream>>>(out, out_size, v);
        return;
    }

    char* ws = (char*)d_ws;
    __bf16* bufA   = (__bf16*)(ws);              // 16 MiB: h -> attnb -> h2
    __bf16* bufB   = (__bf16*)(ws + 16 * MiB);   // 64 MiB: qkvb(48) -> ffb(64)
    float*  x1     = (float*) (ws + 80 * MiB);   // 32 MiB fp32 residual
    __bf16* wqkvT  = (__bf16*)(ws + 112 * MiB);  // 6 MiB
    __bf16* wprojT = (__bf16*)(ws + 118 * MiB);  // 2 MiB
    __bf16* wfcT   = (__bf16*)(ws + 120 * MiB);  // 8 MiB
    __bf16* wmlpT  = (__bf16*)(ws + 128 * MiB);  // 8 MiB

    cvtT_kernel<<<dim3(96, 32),  256, 0, stream>>>(w_qkv,  wqkvT,  1024, 3072);
    cvtT_kernel<<<dim3(32, 32),  256, 0, stream>>>(w_proj, wprojT, 1024, 1024);
    cvtT_kernel<<<dim3(128, 32), 256, 0, stream>>>(w_fc,   wfcT,   1024, 4096);
    cvtT_kernel<<<dim3(32, 128), 256, 0, stream>>>(w_mlp,  wmlpT,  4096, 1024);

    ln_kernel<<<8192, 256, 0, stream>>>(x, ln1_g, ln1_b, bufA);
    gemm256_kernel<0><<<dim3(12, 32), 512, 0, stream>>>(
        bufA, wqkvT, b_qkv, bufB, 8192, 3072, 1024);
    attn_kernel<<<dim3(16, 64), 256, 0, stream>>>(bufB, bufA);
    gemm128x256_kernel<1><<<dim3(4, 64), 512, 0, stream>>>(
        bufA, wprojT, b_proj, x, x1, 8192, 1024, 1024);
    ln_kernel<<<8192, 256, 0, stream>>>(x1, ln2_g, ln2_b, bufA);
    gemm256_kernel<2><<<dim3(16, 32), 512, 0, stream>>>(
        bufA, wfcT, b_fc, bufB, 8192, 4096, 1024);
    gemm128x256_kernel<1><<<dim3(4, 64), 512, 0, stream>>>(
        bufB, wmlpT, b_mlp, x1, out, 8192, 1024, 4096);
}

// Round 6
// 667.687 us; speedup vs baseline: 1.0878x; 1.0186x over previous
//
#include <hip/hip_runtime.h>
#include <hip/hip_bf16.h>

typedef __bf16 bf16x8 __attribute__((ext_vector_type(8)));
typedef __bf16 bf16x4 __attribute__((ext_vector_type(4)));
typedef float f32x4 __attribute__((ext_vector_type(4)));

__device__ __forceinline__ void gload16(const __bf16* g, __bf16* l) {
    __builtin_amdgcn_global_load_lds((const __attribute__((address_space(1))) void*)g,
                                     (__attribute__((address_space(3))) void*)l, 16, 0, 0);
}

__device__ __forceinline__ float gelu_f(float v) {
    float z = 0.7978845608028654f * (v + 0.044715f * v * v * v);
    float e = __expf(2.f * z);
    return 0.5f * v * (2.f - 2.f / (e + 1.f));  // 0.5*v*(1+tanh(z)), overflow-safe
}

// XCD-chunk swizzle (bijective when nwg%8==0)
__device__ __forceinline__ int xcd_swizzle(int flat, int nwg) {
    return (flat & 7) * (nwg >> 3) + (flat >> 3);
}

// ---------------- diagnostic fill (fp32 out) ----------------
__global__ __launch_bounds__(256) void diag_kernel(float* out, int n, float v) {
    int i = blockIdx.x * 256 + threadIdx.x;
    if (i < n) out[i] = v;
}

// ---------------- fused fp32->bf16 convert + transpose: in[K,N] -> out[N,K] ----------------
__global__ __launch_bounds__(256) void cvtT_kernel(
    const float* __restrict__ in, __bf16* __restrict__ out, int K, int N)
{
    __shared__ __bf16 tile[32][33];
    int bx = blockIdx.x * 32, by = blockIdx.y * 32;
    int tx = threadIdx.x & 31, ty = threadIdx.x >> 5;
#pragma unroll
    for (int i = 0; i < 32; i += 8)
        tile[ty + i][tx] = (__bf16)in[(size_t)(by + ty + i) * N + bx + tx];
    __syncthreads();
#pragma unroll
    for (int i = 0; i < 32; i += 8)
        out[(size_t)(bx + ty + i) * K + by + tx] = tile[tx][ty + i];
}

// ---------------- LayerNorm: fp32 in, bf16 out ----------------
__global__ __launch_bounds__(256) void ln_kernel(
    const float* __restrict__ x, const float* __restrict__ g,
    const float* __restrict__ bta, __bf16* __restrict__ out)
{
    const int row = blockIdx.x, t = threadIdx.x;
    const float* xr = x + (size_t)row * 1024;
    float4 xv = ((const float4*)xr)[t];
    float f[4] = {xv.x, xv.y, xv.z, xv.w};
    float s = f[0] + f[1] + f[2] + f[3];
    float ss = f[0]*f[0] + f[1]*f[1] + f[2]*f[2] + f[3]*f[3];
#pragma unroll
    for (int off = 32; off; off >>= 1) {
        s  += __shfl_xor(s, off, 64);
        ss += __shfl_xor(ss, off, 64);
    }
    __shared__ float red[8];
    int lane = t & 63, w = t >> 6;
    if (lane == 0) { red[w] = s; red[4 + w] = ss; }
    __syncthreads();
    s  = red[0] + red[1] + red[2] + red[3];
    ss = red[4] + red[5] + red[6] + red[7];
    float mu = s * (1.f / 1024.f);
    float var = ss * (1.f / 1024.f) - mu * mu;
    float rstd = rsqrtf(fmaxf(var, 0.f) + 1e-5f);
    float4 gv = ((const float4*)g)[t];
    float4 bv = ((const float4*)bta)[t];
    bf16x4 ov;
    ov[0] = (__bf16)((f[0] - mu) * rstd * gv.x + bv.x);
    ov[1] = (__bf16)((f[1] - mu) * rstd * gv.y + bv.y);
    ov[2] = (__bf16)((f[2] - mu) * rstd * gv.z + bv.z);
    ov[3] = (__bf16)((f[3] - mu) * rstd * gv.w + bv.w);
    ((bf16x4*)(out + (size_t)row * 1024))[t] = ov;
}

// ---------------- GEMM 256x256 8-phase (T3+T4+T5, linear LDS): fat-N layers ----------------
// 512 thr = 8 waves (2Mx4N), BK=64, LDS 128 KiB. Counted vmcnt(4), never 0 mid-loop.
// EPI: 0 bias, 2 bias+gelu; bf16 out.
template <int EPI>
__global__ __launch_bounds__(512, 2) void gemm256_kernel(
    const __bf16* __restrict__ A, const __bf16* __restrict__ BT,
    const float* __restrict__ bias, void* __restrict__ Cp, int M, int N, int K)
{
    __shared__ __align__(16) __bf16 lA[2][256 * 64];  // phys = kg*2048 + row*8 + (k&7)
    __shared__ __align__(16) __bf16 lB[2][256 * 64];
    const int t = threadIdx.x;
    const int lane = t & 63, w = t >> 6;
    const int wm = w >> 2, wn = w & 3;          // wave tile: rows wm*128, cols wn*64
    const int q4 = lane >> 4, r16 = lane & 15;
    const int nwg = gridDim.x * gridDim.y;
    const int nf = xcd_swizzle(blockIdx.y * gridDim.x + blockIdx.x, nwg);
    const int bm = (nf / gridDim.x) * 256, bn = (nf % gridDim.x) * 256;

    const int srow = t & 255;
    const int skc  = t >> 8;                    // 0 or 1
    const __bf16* gA = A  + (size_t)(bm + srow) * K + skc * 8;
    const __bf16* gB = BT + (size_t)(bn + srow) * K + skc * 8;
    const int dst = skc * 2048 + srow * 8;      // +j*4096 per gload j

    f32x4 acc[8][4];
    f32x4 zero4 = {0.f, 0.f, 0.f, 0.f};
#pragma unroll
    for (int mi = 0; mi < 8; ++mi)
#pragma unroll
        for (int ni = 0; ni < 4; ++ni) acc[mi][ni] = zero4;

    // prologue: tile0 (A+B) + tile1 A; 12 loads, wait till first 8 landed
#pragma unroll
    for (int j = 0; j < 4; ++j) gload16(gA + j * 16, &lA[0][dst + j * 4096]);
#pragma unroll
    for (int j = 0; j < 4; ++j) gload16(gB + j * 16, &lB[0][dst + j * 4096]);
#pragma unroll
    for (int j = 0; j < 4; ++j) gload16(gA + 64 + j * 16, &lA[1][dst + j * 4096]);
    asm volatile("s_waitcnt vmcnt(4)" ::: "memory");
    __builtin_amdgcn_s_barrier();

    const int nt = K / 64;
    for (int ti = 0; ti < nt; ++ti) {
        const int p = ti & 1;
        bf16x8 af[4][2], bfr[2][2];
#pragma unroll
        for (int q = 0; q < 4; ++q) {
            const int qm = q >> 1, qn = q & 1;
            if (qn == 0) {
#pragma unroll
                for (int mi = 0; mi < 4; ++mi)
#pragma unroll
                    for (int ks = 0; ks < 2; ++ks)
                        af[mi][ks] = *(const bf16x8*)&lA[p][(ks * 4 + q4) * 2048 +
                            (wm * 128 + qm * 64 + mi * 16 + r16) * 8];
            }
#pragma unroll
            for (int ni = 0; ni < 2; ++ni)
#pragma unroll
                for (int ks = 0; ks < 2; ++ks)
                    bfr[ni][ks] = *(const bf16x8*)&lB[p][(ks * 4 + q4) * 2048 +
                        (wn * 64 + qn * 32 + ni * 16 + r16) * 8];
            if (q == 0 && ti + 1 < nt) {
                gload16(gB + (ti + 1) * 64,      &lB[p ^ 1][dst]);
                gload16(gB + (ti + 1) * 64 + 16, &lB[p ^ 1][dst + 4096]);
            }
            if (q == 1 && ti + 1 < nt) {
                gload16(gB + (ti + 1) * 64 + 32, &lB[p ^ 1][dst + 8192]);
                gload16(gB + (ti + 1) * 64 + 48, &lB[p ^ 1][dst + 12288]);
            }
            if (q == 3) {
                if (ti + 2 < nt) {
#pragma unroll
                    for (int j = 0; j < 4; ++j)
                        gload16(gA + (ti + 2) * 64 + j * 16, &lA[p][dst + j * 4096]);
                    asm volatile("s_waitcnt vmcnt(4)" ::: "memory");
                } else {
                    asm volatile("s_waitcnt vmcnt(0)" ::: "memory");
                }
            }
            __builtin_amdgcn_s_barrier();
            asm volatile("s_waitcnt lgkmcnt(0)" ::: "memory");
            __builtin_amdgcn_sched_barrier(0);
            __builtin_amdgcn_s_setprio(1);
#pragma unroll
            for (int mi = 0; mi < 4; ++mi)
#pragma unroll
                for (int ni = 0; ni < 2; ++ni) {
                    f32x4 v = acc[qm * 4 + mi][qn * 2 + ni];
                    v = __builtin_amdgcn_mfma_f32_16x16x32_bf16(af[mi][0], bfr[ni][0], v, 0, 0, 0);
                    v = __builtin_amdgcn_mfma_f32_16x16x32_bf16(af[mi][1], bfr[ni][1], v, 0, 0, 0);
                    acc[qm * 4 + mi][qn * 2 + ni] = v;
                }
            __builtin_amdgcn_s_setprio(0);
            __builtin_amdgcn_sched_barrier(0);
            __builtin_amdgcn_s_barrier();
        }
    }

#pragma unroll
    for (int mi = 0; mi < 8; ++mi) {
#pragma unroll
        for (int ni = 0; ni < 4; ++ni) {
#pragma unroll
            for (int i = 0; i < 4; ++i) {
                int r = bm + wm * 128 + mi * 16 + q4 * 4 + i;
                int c = bn + wn * 64 + ni * 16 + r16;
                float v = acc[mi][ni][i] + bias[c];
                if (EPI == 2) v = gelu_f(v);
                ((__bf16*)Cp)[(size_t)r * N + c] = (__bf16)v;
            }
        }
    }
}

// ---------------- GEMM 128x256 8-phase: skinny-N layers (proj, mlp_proj) ----------------
template <int EPI>   // 1: bias+res
__global__ __launch_bounds__(512, 2) void gemm128x256_kernel(
    const __bf16* __restrict__ A, const __bf16* __restrict__ BT,
    const float* __restrict__ bias, const float* __restrict__ res,
    float* __restrict__ C, int M, int N, int K)
{
    __shared__ __align__(16) __bf16 lA[2][128 * 64];  // phys = kg*1024 + row*8 + (k&7)
    __shared__ __align__(16) __bf16 lB[2][256 * 64];  // phys = kg*2048 + col*8 + (k&7)
    const int t = threadIdx.x;
    const int lane = t & 63, w = t >> 6;
    const int wm = w >> 2, wn = w & 3;          // wave tile: rows wm*64, cols wn*64
    const int q4 = lane >> 4, r16 = lane & 15;
    const int nwg = gridDim.x * gridDim.y;
    const int nf = xcd_swizzle(blockIdx.y * gridDim.x + blockIdx.x, nwg);
    const int bm = (nf / gridDim.x) * 128, bn = (nf % gridDim.x) * 256;

    const int srA = t & 127, kqA = t >> 7;      // kqA in 0..3
    const __bf16* gA = A + (size_t)(bm + srA) * K + kqA * 8;
    const int dstA = kqA * 1024 + srA * 8;
    const int srB = t & 255, skB = t >> 8;      // skB in 0..1
    const __bf16* gB = BT + (size_t)(bn + srB) * K + skB * 8;
    const int dstB = skB * 2048 + srB * 8;

    f32x4 acc[4][4];
    f32x4 zero4 = {0.f, 0.f, 0.f, 0.f};
#pragma unroll
    for (int mi = 0; mi < 4; ++mi)
#pragma unroll
        for (int ni = 0; ni < 4; ++ni) acc[mi][ni] = zero4;

#pragma unroll
    for (int j = 0; j < 2; ++j) gload16(gA + j * 32, &lA[0][dstA + j * 4096]);
#pragma unroll
    for (int j = 0; j < 4; ++j) gload16(gB + j * 16, &lB[0][dstB + j * 4096]);
#pragma unroll
    for (int j = 0; j < 2; ++j) gload16(gA + 64 + j * 32, &lA[1][dstA + j * 4096]);
    asm volatile("s_waitcnt vmcnt(2)" ::: "memory");
    __builtin_amdgcn_s_barrier();

    const int nt = K / 64;
    for (int ti = 0; ti < nt; ++ti) {
        const int p = ti & 1;
        bf16x8 af[2][2], bfr[2][2];
#pragma unroll
        for (int q = 0; q < 4; ++q) {
            const int qm = q >> 1, qn = q & 1;
            if (qn == 0) {
#pragma unroll
                for (int mi = 0; mi < 2; ++mi)
#pragma unroll
                    for (int ks = 0; ks < 2; ++ks)
                        af[mi][ks] = *(const bf16x8*)&lA[p][(ks * 4 + q4) * 1024 +
                            (wm * 64 + qm * 32 + mi * 16 + r16) * 8];
            }
#pragma unroll
            for (int ni = 0; ni < 2; ++ni)
#pragma unroll
                for (int ks = 0; ks < 2; ++ks)
                    bfr[ni][ks] = *(const bf16x8*)&lB[p][(ks * 4 + q4) * 2048 +
                        (wn * 64 + qn * 32 + ni * 16 + r16) * 8];
            if (q == 0 && ti + 1 < nt) {
                gload16(gB + (ti + 1) * 64,      &lB[p ^ 1][dstB]);
                gload16(gB + (ti + 1) * 64 + 16, &lB[p ^ 1][dstB + 4096]);
            }
            if (q == 1 && ti + 1 < nt) {
                gload16(gB + (ti + 1) * 64 + 32, &lB[p ^ 1][dstB + 8192]);
                gload16(gB + (ti + 1) * 64 + 48, &lB[p ^ 1][dstB + 12288]);
            }
            if (q == 3) {
                if (ti + 2 < nt) {
#pragma unroll
                    for (int j = 0; j < 2; ++j)
                        gload16(gA + (ti + 2) * 64 + j * 32, &lA[p][dstA + j * 4096]);
                    asm volatile("s_waitcnt vmcnt(2)" ::: "memory");
                } else {
                    asm volatile("s_waitcnt vmcnt(0)" ::: "memory");
                }
            }
            __builtin_amdgcn_s_barrier();
            asm volatile("s_waitcnt lgkmcnt(0)" ::: "memory");
            __builtin_amdgcn_sched_barrier(0);
            __builtin_amdgcn_s_setprio(1);
#pragma unroll
            for (int mi = 0; mi < 2; ++mi)
#pragma unroll
                for (int ni = 0; ni < 2; ++ni) {
                    f32x4 v = acc[qm * 2 + mi][qn * 2 + ni];
                    v = __builtin_amdgcn_mfma_f32_16x16x32_bf16(af[mi][0], bfr[ni][0], v, 0, 0, 0);
                    v = __builtin_amdgcn_mfma_f32_16x16x32_bf16(af[mi][1], bfr[ni][1], v, 0, 0, 0);
                    acc[qm * 2 + mi][qn * 2 + ni] = v;
                }
            __builtin_amdgcn_s_setprio(0);
            __builtin_amdgcn_sched_barrier(0);
            __builtin_amdgcn_s_barrier();
        }
    }

#pragma unroll
    for (int mi = 0; mi < 4; ++mi) {
#pragma unroll
        for (int ni = 0; ni < 4; ++ni) {
#pragma unroll
            for (int i = 0; i < 4; ++i) {
                int r = bm + wm * 64 + mi * 16 + q4 * 4 + i;
                int c = bn + wn * 64 + ni * 16 + r16;
                float v = acc[mi][ni][i] + bias[c];
                if (EPI == 1) v += res[(size_t)r * N + c];
                C[(size_t)r * N + c] = v;
            }
        }
    }
}

// ---------------- Flash attention (causal), HD=64, T=2048, NH=16 ----------------
// Causal load-balance mapping: with full residency (1024 blocks = 256 CU x 4, CU
// slots spaced 256 apart in flat id), the four co-resident blocks get qt values
// {v, v^15, v^5, v^10} whose work (qt+1) sums to exactly 34 for every v — vs the
// old chunked swizzle which put IDENTICAL qt on all 4 slots (worst CU = 64 units).
__global__ __launch_bounds__(256, 4) void attn_kernel(
    const __bf16* __restrict__ qkv, __bf16* __restrict__ attnb)
{
    __shared__ __align__(16) __bf16 lK[8192];
    __shared__ __align__(16) __bf16 lV[8192];
    __shared__ __align__(16) __bf16 lP[4][512];

    const int t = threadIdx.x, lane = t & 63, w = t >> 6;
    const int q4 = lane >> 4, r16 = lane & 15;
    const int flat = blockIdx.y * 16 + blockIdx.x;   // 0..1023
    const int u = flat & 255, slot = flat >> 8, v5 = u & 15;
    const int cpat = (slot == 0) ? 0 : (slot == 1) ? 15 : (slot == 2) ? 5 : 10;
    const int qt = v5 ^ cpat;
    const int bh = (u >> 4) | (slot << 4);
    const int b = bh >> 4, h = bh & 15;
    const int qb = qt * 128;
    const __bf16* Qb = qkv + (size_t)b * 2048 * 3072 + h * 64;
    const __bf16* Kb = Qb + 1024;
    const __bf16* Vb = Qb + 2048;

    bf16x8 qf[2][2];
#pragma unroll
    for (int p = 0; p < 2; ++p) {
        int qrow = qb + p * 64 + w * 16 + r16;
        qf[p][0] = *(const bf16x8*)(Qb + (size_t)qrow * 3072 + q4 * 8);
        qf[p][1] = *(const bf16x8*)(Qb + (size_t)qrow * 3072 + 32 + q4 * 8);
#pragma unroll
        for (int j = 0; j < 8; ++j) {
            qf[p][0][j] = (__bf16)((float)qf[p][0][j] * 0.125f);
            qf[p][1][j] = (__bf16)((float)qf[p][1][j] * 0.125f);
        }
    }

    f32x4 zero4 = {0.f, 0.f, 0.f, 0.f};
    f32x4 o[2][4];
    float rs[2][4];
#pragma unroll
    for (int p = 0; p < 2; ++p)
#pragma unroll
        for (int i = 0; i < 4; ++i) { o[p][i] = zero4; rs[p][i] = 0.f; }

    const int skey = t & 127;
    const int vkc = t >> 6, svd = t & 63;

    for (int kb = 0; kb < qb + 128; kb += 128) {
        __syncthreads();
#pragma unroll
        for (int c = 0; c < 4; ++c)
            gload16(Kb + (size_t)(kb + skey) * 3072 + (c * 2 + (t >> 7)) * 8,
                    &lK[c * 2048 + t * 8]);
#pragma unroll
        for (int c = 0; c < 4; ++c) {
            int kc = c * 4 + vkc;
            bf16x8 vt;
#pragma unroll
            for (int j = 0; j < 8; ++j)
                vt[j] = Vb[(size_t)(kb + kc * 8 + j) * 3072 + svd];
            *(bf16x8*)&lV[kc * 512 + svd * 8] = vt;
        }
        __syncthreads();

#pragma unroll
        for (int p = 0; p < 2; ++p) {
            const int row0 = qb + p * 64 + w * 16 + q4 * 4;
            const bool interior = (kb + 127) <= (qb + p * 64 + w * 16);

            f32x4 s[8];
#pragma unroll
            for (int kg = 0; kg < 8; ++kg) {
                bf16x8 kfA = *(const bf16x8*)&lK[q4 * 1024 + (kg * 16 + r16) * 8];
                bf16x8 kfB = *(const bf16x8*)&lK[(4 + q4) * 1024 + (kg * 16 + r16) * 8];
                s[kg] = __builtin_amdgcn_mfma_f32_16x16x32_bf16(qf[p][0], kfA, zero4, 0, 0, 0);
                s[kg] = __builtin_amdgcn_mfma_f32_16x16x32_bf16(qf[p][1], kfB, s[kg], 0, 0, 0);
            }

#pragma unroll
            for (int kg = 0; kg < 8; ++kg)
#pragma unroll
                for (int i = 0; i < 4; ++i) {
                    float e = __expf(fminf(s[kg][i], 75.f));
                    if (!interior && (kb + kg * 16 + r16) > (row0 + i)) e = 0.f;
                    s[kg][i] = e;
                    rs[p][i] += e;
                }

#pragma unroll
            for (int c = 0; c < 4; ++c) {
#pragma unroll
                for (int kh = 0; kh < 2; ++kh)
#pragma unroll
                    for (int i = 0; i < 4; ++i)
                        lP[w][(kh * 2 + (r16 >> 3)) * 128 + (q4 * 4 + i) * 8 + (r16 & 7)] =
                            (__bf16)s[c * 2 + kh][i];
                asm volatile("s_waitcnt lgkmcnt(0)" ::: "memory");
                bf16x8 pf = *(const bf16x8*)&lP[w][q4 * 128 + r16 * 8];
#pragma unroll
                for (int ci = 0; ci < 4; ++ci) {
                    bf16x8 vf = *(const bf16x8*)&lV[(c * 4 + q4) * 512 + (ci * 16 + r16) * 8];
                    o[p][ci] = __builtin_amdgcn_mfma_f32_16x16x32_bf16(pf, vf, o[p][ci], 0, 0, 0);
                }
            }
        }
    }

#pragma unroll
    for (int p = 0; p < 2; ++p) {
#pragma unroll
        for (int off = 8; off; off >>= 1)
#pragma unroll
            for (int i = 0; i < 4; ++i) rs[p][i] += __shfl_xor(rs[p][i], off, 64);
#pragma unroll
        for (int ci = 0; ci < 4; ++ci)
#pragma unroll
            for (int i = 0; i < 4; ++i) {
                int trow = qb + p * 64 + w * 16 + q4 * 4 + i;
                float inv_l = (rs[p][i] > 0.f) ? (1.f / rs[p][i]) : 0.f;
                attnb[(size_t)(b * 2048 + trow) * 1024 + h * 64 + ci * 16 + r16] =
                    (__bf16)(o[p][ci][i] * inv_l);
            }
    }
}

// ---------------- launcher ----------------
extern "C" void kernel_launch(void* const* d_in, const int* in_sizes, int n_in,
                              void* d_out, int out_size, void* d_ws, size_t ws_size,
                              hipStream_t stream)
{
    const float* x      = (const float*)d_in[0];
    const float* ln1_g  = (const float*)d_in[1];
    const float* ln1_b  = (const float*)d_in[2];
    const float* w_qkv  = (const float*)d_in[3];
    const float* b_qkv  = (const float*)d_in[4];
    const float* w_proj = (const float*)d_in[5];
    const float* b_proj = (const float*)d_in[6];
    const float* ln2_g  = (const float*)d_in[7];
    const float* ln2_b  = (const float*)d_in[8];
    const float* w_fc   = (const float*)d_in[9];
    const float* b_fc   = (const float*)d_in[10];
    const float* w_mlp  = (const float*)d_in[11];
    const float* b_mlp  = (const float*)d_in[12];
    float* out = (float*)d_out;

    const size_t MiB = (size_t)1 << 20;
    if (ws_size < 136 * MiB) {
        float v = 1000.f + (float)(ws_size >> 20);
        diag_kernel<<<(out_size + 255) / 256, 256, 0, stream>>>(out, out_size, v);
        return;
    }

    char* ws = (char*)d_ws;
    __bf16* bufA   = (__bf16*)(ws);              // 16 MiB: h -> attnb -> h2
    __bf16* bufB   = (__bf16*)(ws + 16 * MiB);   // 64 MiB: qkvb(48) -> ffb(64)
    float*  x1     = (float*) (ws + 80 * MiB);   // 32 MiB fp32 residual
    __bf16* wqkvT  = (__bf16*)(ws + 112 * MiB);  // 6 MiB
    __bf16* wprojT = (__bf16*)(ws + 118 * MiB);  // 2 MiB
    __bf16* wfcT   = (__bf16*)(ws + 120 * MiB);  // 8 MiB
    __bf16* wmlpT  = (__bf16*)(ws + 128 * MiB);  // 8 MiB

    cvtT_kernel<<<dim3(96, 32),  256, 0, stream>>>(w_qkv,  wqkvT,  1024, 3072);
    cvtT_kernel<<<dim3(32, 32),  256, 0, stream>>>(w_proj, wprojT, 1024, 1024);
    cvtT_kernel<<<dim3(128, 32), 256, 0, stream>>>(w_fc,   wfcT,   1024, 4096);
    cvtT_kernel<<<dim3(32, 128), 256, 0, stream>>>(w_mlp,  wmlpT,  4096, 1024);

    ln_kernel<<<8192, 256, 0, stream>>>(x, ln1_g, ln1_b, bufA);
    gemm256_kernel<0><<<dim3(12, 32), 512, 0, stream>>>(
        bufA, wqkvT, b_qkv, bufB, 8192, 3072, 1024);
    attn_kernel<<<dim3(16, 64), 256, 0, stream>>>(bufB, bufA);
    gemm128x256_kernel<1><<<dim3(4, 64), 512, 0, stream>>>(
        bufA, wprojT, b_proj, x, x1, 8192, 1024, 1024);
    ln_kernel<<<8192, 256, 0, stream>>>(x1, ln2_g, ln2_b, bufA);
    gemm256_kernel<2><<<dim3(16, 32), 512, 0, stream>>>(
        bufA, wfcT, b_fc, bufB, 8192, 4096, 1024);
    gemm128x256_kernel<1><<<dim3(4, 64), 512, 0, stream>>>(
        bufB, wmlpT, b_mlp, x1, out, 8192, 1024, 4096);
}

// Round 7
// 652.133 us; speedup vs baseline: 1.1138x; 1.0239x over previous
//
#include <hip/hip_runtime.h>
#include <hip/hip_bf16.h>

typedef __bf16 bf16x8 __attribute__((ext_vector_type(8)));
typedef __bf16 bf16x4 __attribute__((ext_vector_type(4)));
typedef float f32x4 __attribute__((ext_vector_type(4)));

__device__ __forceinline__ void gload16(const __bf16* g, __bf16* l) {
    __builtin_amdgcn_global_load_lds((const __attribute__((address_space(1))) void*)g,
                                     (__attribute__((address_space(3))) void*)l, 16, 0, 0);
}

__device__ __forceinline__ float gelu_f(float v) {
    float z = 0.7978845608028654f * (v + 0.044715f * v * v * v);
    float e = __expf(2.f * z);
    return 0.5f * v * (2.f - 2.f / (e + 1.f));  // 0.5*v*(1+tanh(z)), overflow-safe
}

// XCD-chunk swizzle (bijective when nwg%8==0)
__device__ __forceinline__ int xcd_swizzle(int flat, int nwg) {
    return (flat & 7) * (nwg >> 3) + (flat >> 3);
}

// ---------------- diagnostic fill (fp32 out) ----------------
__global__ __launch_bounds__(256) void diag_kernel(float* out, int n, float v) {
    int i = blockIdx.x * 256 + threadIdx.x;
    if (i < n) out[i] = v;
}

// ---------------- fused fp32->bf16 convert + transpose: in[K,N] -> out[N,K] ----------------
__global__ __launch_bounds__(256) void cvtT_kernel(
    const float* __restrict__ in, __bf16* __restrict__ out, int K, int N)
{
    __shared__ __bf16 tile[32][33];
    int bx = blockIdx.x * 32, by = blockIdx.y * 32;
    int tx = threadIdx.x & 31, ty = threadIdx.x >> 5;
#pragma unroll
    for (int i = 0; i < 32; i += 8)
        tile[ty + i][tx] = (__bf16)in[(size_t)(by + ty + i) * N + bx + tx];
    __syncthreads();
#pragma unroll
    for (int i = 0; i < 32; i += 8)
        out[(size_t)(bx + ty + i) * K + by + tx] = tile[tx][ty + i];
}

// ---------------- LayerNorm: fp32 in, bf16 out ----------------
__global__ __launch_bounds__(256) void ln_kernel(
    const float* __restrict__ x, const float* __restrict__ g,
    const float* __restrict__ bta, __bf16* __restrict__ out)
{
    const int row = blockIdx.x, t = threadIdx.x;
    const float* xr = x + (size_t)row * 1024;
    float4 xv = ((const float4*)xr)[t];
    float f[4] = {xv.x, xv.y, xv.z, xv.w};
    float s = f[0] + f[1] + f[2] + f[3];
    float ss = f[0]*f[0] + f[1]*f[1] + f[2]*f[2] + f[3]*f[3];
#pragma unroll
    for (int off = 32; off; off >>= 1) {
        s  += __shfl_xor(s, off, 64);
        ss += __shfl_xor(ss, off, 64);
    }
    __shared__ float red[8];
    int lane = t & 63, w = t >> 6;
    if (lane == 0) { red[w] = s; red[4 + w] = ss; }
    __syncthreads();
    s  = red[0] + red[1] + red[2] + red[3];
    ss = red[4] + red[5] + red[6] + red[7];
    float mu = s * (1.f / 1024.f);
    float var = ss * (1.f / 1024.f) - mu * mu;
    float rstd = rsqrtf(fmaxf(var, 0.f) + 1e-5f);
    float4 gv = ((const float4*)g)[t];
    float4 bv = ((const float4*)bta)[t];
    bf16x4 ov;
    ov[0] = (__bf16)((f[0] - mu) * rstd * gv.x + bv.x);
    ov[1] = (__bf16)((f[1] - mu) * rstd * gv.y + bv.y);
    ov[2] = (__bf16)((f[2] - mu) * rstd * gv.z + bv.z);
    ov[3] = (__bf16)((f[3] - mu) * rstd * gv.w + bv.w);
    ((bf16x4*)(out + (size_t)row * 1024))[t] = ov;
}

// ---------------- GEMM 256x256 8-phase (T3+T4+T5, linear LDS): fat-N layers ----------------
// 512 thr = 8 waves (2Mx4N), BK=64, LDS 128 KiB. Counted vmcnt(4), never 0 mid-loop.
// EPI: 0 bias, 2 bias+gelu; bf16 out.
template <int EPI>
__global__ __launch_bounds__(512, 2) void gemm256_kernel(
    const __bf16* __restrict__ A, const __bf16* __restrict__ BT,
    const float* __restrict__ bias, void* __restrict__ Cp, int M, int N, int K)
{
    __shared__ __align__(16) __bf16 lA[2][256 * 64];  // phys = kg*2048 + row*8 + (k&7)
    __shared__ __align__(16) __bf16 lB[2][256 * 64];
    const int t = threadIdx.x;
    const int lane = t & 63, w = t >> 6;
    const int wm = w >> 2, wn = w & 3;          // wave tile: rows wm*128, cols wn*64
    const int q4 = lane >> 4, r16 = lane & 15;
    const int nwg = gridDim.x * gridDim.y;
    const int nf = xcd_swizzle(blockIdx.y * gridDim.x + blockIdx.x, nwg);
    const int bm = (nf / gridDim.x) * 256, bn = (nf % gridDim.x) * 256;

    const int srow = t & 255;
    const int skc  = t >> 8;                    // 0 or 1
    const __bf16* gA = A  + (size_t)(bm + srow) * K + skc * 8;
    const __bf16* gB = BT + (size_t)(bn + srow) * K + skc * 8;
    const int dst = skc * 2048 + srow * 8;      // +j*4096 per gload j

    f32x4 acc[8][4];
    f32x4 zero4 = {0.f, 0.f, 0.f, 0.f};
#pragma unroll
    for (int mi = 0; mi < 8; ++mi)
#pragma unroll
        for (int ni = 0; ni < 4; ++ni) acc[mi][ni] = zero4;

    // prologue: tile0 (A+B) + tile1 A; 12 loads, wait till first 8 landed
#pragma unroll
    for (int j = 0; j < 4; ++j) gload16(gA + j * 16, &lA[0][dst + j * 4096]);
#pragma unroll
    for (int j = 0; j < 4; ++j) gload16(gB + j * 16, &lB[0][dst + j * 4096]);
#pragma unroll
    for (int j = 0; j < 4; ++j) gload16(gA + 64 + j * 16, &lA[1][dst + j * 4096]);
    asm volatile("s_waitcnt vmcnt(4)" ::: "memory");
    __builtin_amdgcn_s_barrier();

    const int nt = K / 64;
    for (int ti = 0; ti < nt; ++ti) {
        const int p = ti & 1;
        bf16x8 af[4][2], bfr[2][2];
#pragma unroll
        for (int q = 0; q < 4; ++q) {
            const int qm = q >> 1, qn = q & 1;
            if (qn == 0) {
#pragma unroll
                for (int mi = 0; mi < 4; ++mi)
#pragma unroll
                    for (int ks = 0; ks < 2; ++ks)
                        af[mi][ks] = *(const bf16x8*)&lA[p][(ks * 4 + q4) * 2048 +
                            (wm * 128 + qm * 64 + mi * 16 + r16) * 8];
            }
#pragma unroll
            for (int ni = 0; ni < 2; ++ni)
#pragma unroll
                for (int ks = 0; ks < 2; ++ks)
                    bfr[ni][ks] = *(const bf16x8*)&lB[p][(ks * 4 + q4) * 2048 +
                        (wn * 64 + qn * 32 + ni * 16 + r16) * 8];
            if (q == 0 && ti + 1 < nt) {
                gload16(gB + (ti + 1) * 64,      &lB[p ^ 1][dst]);
                gload16(gB + (ti + 1) * 64 + 16, &lB[p ^ 1][dst + 4096]);
            }
            if (q == 1 && ti + 1 < nt) {
                gload16(gB + (ti + 1) * 64 + 32, &lB[p ^ 1][dst + 8192]);
                gload16(gB + (ti + 1) * 64 + 48, &lB[p ^ 1][dst + 12288]);
            }
            if (q == 3) {
                if (ti + 2 < nt) {
#pragma unroll
                    for (int j = 0; j < 4; ++j)
                        gload16(gA + (ti + 2) * 64 + j * 16, &lA[p][dst + j * 4096]);
                    asm volatile("s_waitcnt vmcnt(4)" ::: "memory");
                } else {
                    asm volatile("s_waitcnt vmcnt(0)" ::: "memory");
                }
            }
            __builtin_amdgcn_s_barrier();
            asm volatile("s_waitcnt lgkmcnt(0)" ::: "memory");
            __builtin_amdgcn_sched_barrier(0);
            __builtin_amdgcn_s_setprio(1);
#pragma unroll
            for (int mi = 0; mi < 4; ++mi)
#pragma unroll
                for (int ni = 0; ni < 2; ++ni) {
                    f32x4 v = acc[qm * 4 + mi][qn * 2 + ni];
                    v = __builtin_amdgcn_mfma_f32_16x16x32_bf16(af[mi][0], bfr[ni][0], v, 0, 0, 0);
                    v = __builtin_amdgcn_mfma_f32_16x16x32_bf16(af[mi][1], bfr[ni][1], v, 0, 0, 0);
                    acc[qm * 4 + mi][qn * 2 + ni] = v;
                }
            __builtin_amdgcn_s_setprio(0);
            __builtin_amdgcn_sched_barrier(0);
            __builtin_amdgcn_s_barrier();
        }
    }

#pragma unroll
    for (int mi = 0; mi < 8; ++mi) {
#pragma unroll
        for (int ni = 0; ni < 4; ++ni) {
#pragma unroll
            for (int i = 0; i < 4; ++i) {
                int r = bm + wm * 128 + mi * 16 + q4 * 4 + i;
                int c = bn + wn * 64 + ni * 16 + r16;
                float v = acc[mi][ni][i] + bias[c];
                if (EPI == 2) v = gelu_f(v);
                ((__bf16*)Cp)[(size_t)r * N + c] = (__bf16)v;
            }
        }
    }
}

// ---------------- GEMM 128x256 2-phase/K-tile (16 MFMA per phase): proj, mlp_proj ----
// 8 waves (2Mx4N), wave tile 64x64, BK=64, LDS 96 KiB. Phase split along N:
//   phase 0 (qn=0): ds-read ALL af[4][2] + bfr(N-half 0); stage B(t+1); 16 MFMA
//   phase 1 (qn=1): ds-read bfr(N-half 1);               stage A(t+2); 16 MFMA
// Race-safety: phase 1 reads only lB[p]; af reads of lA[p] completed before phase-0
// trailing barrier, so the A(t+2) gloads into lA[p] cannot corrupt them.
// vmcnt ledger (steady): queue at wait = [B(t+1)x4, A(t+2)x2] -> vmcnt(2); tail -> 0.
template <int EPI>   // 1: bias+res
__global__ __launch_bounds__(512, 2) void gemm128x256_kernel(
    const __bf16* __restrict__ A, const __bf16* __restrict__ BT,
    const float* __restrict__ bias, const float* __restrict__ res,
    float* __restrict__ C, int M, int N, int K)
{
    __shared__ __align__(16) __bf16 lA[2][128 * 64];  // phys = kg*1024 + row*8 + (k&7)
    __shared__ __align__(16) __bf16 lB[2][256 * 64];  // phys = kg*2048 + col*8 + (k&7)
    const int t = threadIdx.x;
    const int lane = t & 63, w = t >> 6;
    const int wm = w >> 2, wn = w & 3;          // wave tile: rows wm*64, cols wn*64
    const int q4 = lane >> 4, r16 = lane & 15;
    const int nwg = gridDim.x * gridDim.y;
    const int nf = xcd_swizzle(blockIdx.y * gridDim.x + blockIdx.x, nwg);
    const int bm = (nf / gridDim.x) * 128, bn = (nf % gridDim.x) * 256;

    const int srA = t & 127, kqA = t >> 7;      // kqA in 0..3
    const __bf16* gA = A + (size_t)(bm + srA) * K + kqA * 8;
    const int dstA = kqA * 1024 + srA * 8;
    const int srB = t & 255, skB = t >> 8;      // skB in 0..1
    const __bf16* gB = BT + (size_t)(bn + srB) * K + skB * 8;
    const int dstB = skB * 2048 + srB * 8;

    f32x4 acc[4][4];
    f32x4 zero4 = {0.f, 0.f, 0.f, 0.f};
#pragma unroll
    for (int mi = 0; mi < 4; ++mi)
#pragma unroll
        for (int ni = 0; ni < 4; ++ni) acc[mi][ni] = zero4;

#pragma unroll
    for (int j = 0; j < 2; ++j) gload16(gA + j * 32, &lA[0][dstA + j * 4096]);
#pragma unroll
    for (int j = 0; j < 4; ++j) gload16(gB + j * 16, &lB[0][dstB + j * 4096]);
#pragma unroll
    for (int j = 0; j < 2; ++j) gload16(gA + 64 + j * 32, &lA[1][dstA + j * 4096]);
    asm volatile("s_waitcnt vmcnt(2)" ::: "memory");
    __builtin_amdgcn_s_barrier();

    const int nt = K / 64;
    for (int ti = 0; ti < nt; ++ti) {
        const int p = ti & 1;
        bf16x8 af[4][2], bfr[2][2];
#pragma unroll
        for (int qn = 0; qn < 2; ++qn) {
            if (qn == 0) {
#pragma unroll
                for (int mi = 0; mi < 4; ++mi)
#pragma unroll
                    for (int ks = 0; ks < 2; ++ks)
                        af[mi][ks] = *(const bf16x8*)&lA[p][(ks * 4 + q4) * 1024 +
                            (wm * 64 + mi * 16 + r16) * 8];
            }
#pragma unroll
            for (int ni = 0; ni < 2; ++ni)
#pragma unroll
                for (int ks = 0; ks < 2; ++ks)
                    bfr[ni][ks] = *(const bf16x8*)&lB[p][(ks * 4 + q4) * 2048 +
                        (wn * 64 + qn * 32 + ni * 16 + r16) * 8];
            if (qn == 0 && ti + 1 < nt) {
                gload16(gB + (ti + 1) * 64,      &lB[p ^ 1][dstB]);
                gload16(gB + (ti + 1) * 64 + 16, &lB[p ^ 1][dstB + 4096]);
                gload16(gB + (ti + 1) * 64 + 32, &lB[p ^ 1][dstB + 8192]);
                gload16(gB + (ti + 1) * 64 + 48, &lB[p ^ 1][dstB + 12288]);
            }
            if (qn == 1) {
                if (ti + 2 < nt) {
#pragma unroll
                    for (int j = 0; j < 2; ++j)
                        gload16(gA + (ti + 2) * 64 + j * 32, &lA[p][dstA + j * 4096]);
                    asm volatile("s_waitcnt vmcnt(2)" ::: "memory");
                } else {
                    asm volatile("s_waitcnt vmcnt(0)" ::: "memory");
                }
            }
            __builtin_amdgcn_s_barrier();
            asm volatile("s_waitcnt lgkmcnt(0)" ::: "memory");
            __builtin_amdgcn_sched_barrier(0);
            __builtin_amdgcn_s_setprio(1);
#pragma unroll
            for (int mi = 0; mi < 4; ++mi)
#pragma unroll
                for (int ni = 0; ni < 2; ++ni) {
                    f32x4 v = acc[mi][qn * 2 + ni];
                    v = __builtin_amdgcn_mfma_f32_16x16x32_bf16(af[mi][0], bfr[ni][0], v, 0, 0, 0);
                    v = __builtin_amdgcn_mfma_f32_16x16x32_bf16(af[mi][1], bfr[ni][1], v, 0, 0, 0);
                    acc[mi][qn * 2 + ni] = v;
                }
            __builtin_amdgcn_s_setprio(0);
            __builtin_amdgcn_sched_barrier(0);
            __builtin_amdgcn_s_barrier();
        }
    }

#pragma unroll
    for (int mi = 0; mi < 4; ++mi) {
#pragma unroll
        for (int ni = 0; ni < 4; ++ni) {
#pragma unroll
            for (int i = 0; i < 4; ++i) {
                int r = bm + wm * 64 + mi * 16 + q4 * 4 + i;
                int c = bn + wn * 64 + ni * 16 + r16;
                float v = acc[mi][ni][i] + bias[c];
                if (EPI == 1) v += res[(size_t)r * N + c];
                C[(size_t)r * N + c] = v;
            }
        }
    }
}

// ---------------- Flash attention (causal), HD=64, T=2048, NH=16 ----------------
// Causal load-balance mapping: co-resident CU slots get qt values {v, v^15, v^5, v^10}
// whose work (qt+1) sums to exactly 34 for every v.
__global__ __launch_bounds__(256, 4) void attn_kernel(
    const __bf16* __restrict__ qkv, __bf16* __restrict__ attnb)
{
    __shared__ __align__(16) __bf16 lK[8192];
    __shared__ __align__(16) __bf16 lV[8192];
    __shared__ __align__(16) __bf16 lP[4][512];

    const int t = threadIdx.x, lane = t & 63, w = t >> 6;
    const int q4 = lane >> 4, r16 = lane & 15;
    const int flat = blockIdx.y * 16 + blockIdx.x;   // 0..1023
    const int u = flat & 255, slot = flat >> 8, v5 = u & 15;
    const int cpat = (slot == 0) ? 0 : (slot == 1) ? 15 : (slot == 2) ? 5 : 10;
    const int qt = v5 ^ cpat;
    const int bh = (u >> 4) | (slot << 4);
    const int b = bh >> 4, h = bh & 15;
    const int qb = qt * 128;
    const __bf16* Qb = qkv + (size_t)b * 2048 * 3072 + h * 64;
    const __bf16* Kb = Qb + 1024;
    const __bf16* Vb = Qb + 2048;

    bf16x8 qf[2][2];
#pragma unroll
    for (int p = 0; p < 2; ++p) {
        int qrow = qb + p * 64 + w * 16 + r16;
        qf[p][0] = *(const bf16x8*)(Qb + (size_t)qrow * 3072 + q4 * 8);
        qf[p][1] = *(const bf16x8*)(Qb + (size_t)qrow * 3072 + 32 + q4 * 8);
#pragma unroll
        for (int j = 0; j < 8; ++j) {
            qf[p][0][j] = (__bf16)((float)qf[p][0][j] * 0.125f);
            qf[p][1][j] = (__bf16)((float)qf[p][1][j] * 0.125f);
        }
    }

    f32x4 zero4 = {0.f, 0.f, 0.f, 0.f};
    f32x4 o[2][4];
    float rs[2][4];
#pragma unroll
    for (int p = 0; p < 2; ++p)
#pragma unroll
        for (int i = 0; i < 4; ++i) { o[p][i] = zero4; rs[p][i] = 0.f; }

    const int skey = t & 127;
    const int vkc = t >> 6, svd = t & 63;

    for (int kb = 0; kb < qb + 128; kb += 128) {
        __syncthreads();
#pragma unroll
        for (int c = 0; c < 4; ++c)
            gload16(Kb + (size_t)(kb + skey) * 3072 + (c * 2 + (t >> 7)) * 8,
                    &lK[c * 2048 + t * 8]);
#pragma unroll
        for (int c = 0; c < 4; ++c) {
            int kc = c * 4 + vkc;
            bf16x8 vt;
#pragma unroll
            for (int j = 0; j < 8; ++j)
                vt[j] = Vb[(size_t)(kb + kc * 8 + j) * 3072 + svd];
            *(bf16x8*)&lV[kc * 512 + svd * 8] = vt;
        }
        __syncthreads();

#pragma unroll
        for (int p = 0; p < 2; ++p) {
            const int row0 = qb + p * 64 + w * 16 + q4 * 4;
            const bool interior = (kb + 127) <= (qb + p * 64 + w * 16);

            f32x4 s[8];
#pragma unroll
            for (int kg = 0; kg < 8; ++kg) {
                bf16x8 kfA = *(const bf16x8*)&lK[q4 * 1024 + (kg * 16 + r16) * 8];
                bf16x8 kfB = *(const bf16x8*)&lK[(4 + q4) * 1024 + (kg * 16 + r16) * 8];
                s[kg] = __builtin_amdgcn_mfma_f32_16x16x32_bf16(qf[p][0], kfA, zero4, 0, 0, 0);
                s[kg] = __builtin_amdgcn_mfma_f32_16x16x32_bf16(qf[p][1], kfB, s[kg], 0, 0, 0);
            }

#pragma unroll
            for (int kg = 0; kg < 8; ++kg)
#pragma unroll
                for (int i = 0; i < 4; ++i) {
                    float e = __expf(fminf(s[kg][i], 75.f));
                    if (!interior && (kb + kg * 16 + r16) > (row0 + i)) e = 0.f;
                    s[kg][i] = e;
                    rs[p][i] += e;
                }

#pragma unroll
            for (int c = 0; c < 4; ++c) {
#pragma unroll
                for (int kh = 0; kh < 2; ++kh)
#pragma unroll
                    for (int i = 0; i < 4; ++i)
                        lP[w][(kh * 2 + (r16 >> 3)) * 128 + (q4 * 4 + i) * 8 + (r16 & 7)] =
                            (__bf16)s[c * 2 + kh][i];
                asm volatile("s_waitcnt lgkmcnt(0)" ::: "memory");
                bf16x8 pf = *(const bf16x8*)&lP[w][q4 * 128 + r16 * 8];
#pragma unroll
                for (int ci = 0; ci < 4; ++ci) {
                    bf16x8 vf = *(const bf16x8*)&lV[(c * 4 + q4) * 512 + (ci * 16 + r16) * 8];
                    o[p][ci] = __builtin_amdgcn_mfma_f32_16x16x32_bf16(pf, vf, o[p][ci], 0, 0, 0);
                }
            }
        }
    }

#pragma unroll
    for (int p = 0; p < 2; ++p) {
#pragma unroll
        for (int off = 8; off; off >>= 1)
#pragma unroll
            for (int i = 0; i < 4; ++i) rs[p][i] += __shfl_xor(rs[p][i], off, 64);
#pragma unroll
        for (int ci = 0; ci < 4; ++ci)
#pragma unroll
            for (int i = 0; i < 4; ++i) {
                int trow = qb + p * 64 + w * 16 + q4 * 4 + i;
                float inv_l = (rs[p][i] > 0.f) ? (1.f / rs[p][i]) : 0.f;
                attnb[(size_t)(b * 2048 + trow) * 1024 + h * 64 + ci * 16 + r16] =
                    (__bf16)(o[p][ci][i] * inv_l);
            }
    }
}

// ---------------- launcher ----------------
extern "C" void kernel_launch(void* const* d_in, const int* in_sizes, int n_in,
                              void* d_out, int out_size, void* d_ws, size_t ws_size,
                              hipStream_t stream)
{
    const float* x      = (const float*)d_in[0];
    const float* ln1_g  = (const float*)d_in[1];
    const float* ln1_b  = (const float*)d_in[2];
    const float* w_qkv  = (const float*)d_in[3];
    const float* b_qkv  = (const float*)d_in[4];
    const float* w_proj = (const float*)d_in[5];
    const float* b_proj = (const float*)d_in[6];
    const float* ln2_g  = (const float*)d_in[7];
    const float* ln2_b  = (const float*)d_in[8];
    const float* w_fc   = (const float*)d_in[9];
    const float* b_fc   = (const float*)d_in[10];
    const float* w_mlp  = (const float*)d_in[11];
    const float* b_mlp  = (const float*)d_in[12];
    float* out = (float*)d_out;

    const size_t MiB = (size_t)1 << 20;
    if (ws_size < 136 * MiB) {
        float v = 1000.f + (float)(ws_size >> 20);
        diag_kernel<<<(out_size + 255) / 256, 256, 0, stream>>>(out, out_size, v);
        return;
    }

    char* ws = (char*)d_ws;
    __bf16* bufA   = (__bf16*)(ws);              // 16 MiB: h -> attnb -> h2
    __bf16* bufB   = (__bf16*)(ws + 16 * MiB);   // 64 MiB: qkvb(48) -> ffb(64)
    float*  x1     = (float*) (ws + 80 * MiB);   // 32 MiB fp32 residual
    __bf16* wqkvT  = (__bf16*)(ws + 112 * MiB);  // 6 MiB
    __bf16* wprojT = (__bf16*)(ws + 118 * MiB);  // 2 MiB
    __bf16* wfcT   = (__bf16*)(ws + 120 * MiB);  // 8 MiB
    __bf16* wmlpT  = (__bf16*)(ws + 128 * MiB);  // 8 MiB

    cvtT_kernel<<<dim3(96, 32),  256, 0, stream>>>(w_qkv,  wqkvT,  1024, 3072);
    cvtT_kernel<<<dim3(32, 32),  256, 0, stream>>>(w_proj, wprojT, 1024, 1024);
    cvtT_kernel<<<dim3(128, 32), 256, 0, stream>>>(w_fc,   wfcT,   1024, 4096);
    cvtT_kernel<<<dim3(32, 128), 256, 0, stream>>>(w_mlp,  wmlpT,  4096, 1024);

    ln_kernel<<<8192, 256, 0, stream>>>(x, ln1_g, ln1_b, bufA);
    gemm256_kernel<0><<<dim3(12, 32), 512, 0, stream>>>(
        bufA, wqkvT, b_qkv, bufB, 8192, 3072, 1024);
    attn_kernel<<<dim3(16, 64), 256, 0, stream>>>(bufB, bufA);
    gemm128x256_kernel<1><<<dim3(4, 64), 512, 0, stream>>>(
        bufA, wprojT, b_proj, x, x1, 8192, 1024, 1024);
    ln_kernel<<<8192, 256, 0, stream>>>(x1, ln2_g, ln2_b, bufA);
    gemm256_kernel<2><<<dim3(16, 32), 512, 0, stream>>>(
        bufA, wfcT, b_fc, bufB, 8192, 4096, 1024);
    gemm128x256_kernel<1><<<dim3(4, 64), 512, 0, stream>>>(
        bufB, wmlpT, b_mlp, x1, out, 8192, 1024, 4096);
}